// Round 8
// baseline (1562.853 us; speedup 1.0000x reference)
//
#include <hip/hip_runtime.h>
#include <cstdint>

constexpr int Bn = 128, Tn = 1024, Dn = 64, Hn = 256, On = 128;
constexpr int HSL = 36;  // padded LDS slice stride (32 data + 4 pad)

typedef float v2f __attribute__((ext_vector_type(2)));

__device__ __forceinline__ float fast_tanh(float x) {
  float e = __expf(2.0f * x);
  return 1.0f - 2.0f / (e + 1.0f);
}

template <int CTRL>
__device__ __forceinline__ float dpp_add(float v) {
  int s = __builtin_amdgcn_update_dpp(0, __float_as_int(v), CTRL, 0xF, 0xF, true);
  return v + __int_as_float(s);
}
__device__ __forceinline__ float row16_sum(float v) {
  v = dpp_add<0xB1>(v);   // quad_perm xor1
  v = dpp_add<0x4E>(v);   // quad_perm xor2
  v = dpp_add<0x141>(v);  // ROW_HALF_MIRROR == xor4
  v = dpp_add<0x140>(v);  // ROW_MIRROR == xor8
  return v;
}

__device__ __forceinline__ float sel8(int ks, float s0, float s1, float s2,
                                      float s3, float s4, float s5, float s6,
                                      float s7) {
  float u0 = (ks & 1) ? s1 : s0;
  float u1 = (ks & 1) ? s3 : s2;
  float u2 = (ks & 1) ? s5 : s4;
  float u3 = (ks & 1) ? s7 : s6;
  float v0 = (ks & 2) ? u1 : u0;
  float v1 = (ks & 2) ? u3 : u2;
  return (ks & 4) ? v1 : v0;
}

// ---------------------------------------------------------------------------
// Fully pipelined 3-stage kernel (384 WGs):
//   WGs [0,128):   role A — scan1 producer; releases flagsA[b] per 32-step blk
//   WGs [128,256): role B — u2 = h1@Wx2+b2 consumer (in-place); releases flagsB
//   WGs [256,384): role C — scan2 consumer of u2; writes hfinal
// DAG A->B->C, all flags use drained-barrier->release / spin-acquire protocol
// (HW-validated in R7: absmax was bit-exact). All 384 WGs co-resident:
// 4 WGs/CU capacity (LDS 36.9 KB, 512 thr), need avg 1.5.
// ---------------------------------------------------------------------------
__global__ __launch_bounds__(512, 2) void stage1_kernel(
    const float* __restrict__ x,    // [B,T,64]
    const float* __restrict__ Wx1,  // [64,256]
    const float* __restrict__ Wh1,  // [256,256]
    const float* __restrict__ b1,   // [256]
    const float* __restrict__ Wx2,  // [256,256]
    const float* __restrict__ b2,   // [256]
    const float* __restrict__ Wh2,  // [256,256]
    float* __restrict__ h1buf,      // [B,T,256] h1 then (in-place) u2
    float* __restrict__ hfinal,     // [B,256]
    int* __restrict__ flagsA,       // [B]
    int* __restrict__ flagsB) {     // [B]
  __shared__ alignas(16) float smem[32 * 8 * HSL];  // 36.9 KB union of roles
  const int tid = threadIdx.x;
  const int ks = tid & 15;
  const int cg = tid >> 4;
  const int col0 = 8 * cg;
  const int jcol = col0 + (ks & 7);
  const bool writer = (ks < 8);

  if (blockIdx.x < Bn) {
    // ================= ROLE A: scan1 producer =================
    const int b = blockIdx.x;
    const float* xb = x + (size_t)b * Tn * Dn;
    float* hb = h1buf + (size_t)b * Tn * Hn;
    float* hc0 = smem;          // [2][8*HSL]
    float* xs0 = smem + 576;    // [2][2048]

    v2f wh[8][8];
    #pragma unroll
    for (int p = 0; p < 8; ++p) {
      const float* r0 = Wh1 + (size_t)(16 * ks + 2 * p) * Hn + col0;
      float4 a0 = *(const float4*)r0, a1 = *(const float4*)(r0 + 4);
      float4 c0 = *(const float4*)(r0 + Hn), c1 = *(const float4*)(r0 + Hn + 4);
      wh[p][0] = (v2f){a0.x, c0.x}; wh[p][1] = (v2f){a0.y, c0.y};
      wh[p][2] = (v2f){a0.z, c0.z}; wh[p][3] = (v2f){a0.w, c0.w};
      wh[p][4] = (v2f){a1.x, c1.x}; wh[p][5] = (v2f){a1.y, c1.y};
      wh[p][6] = (v2f){a1.z, c1.z}; wh[p][7] = (v2f){a1.w, c1.w};
    }
    v2f wx[2][8];
    #pragma unroll
    for (int p = 0; p < 2; ++p) {
      const float* r0 = Wx1 + (size_t)(4 * ks + 2 * p) * Hn + col0;
      float4 a0 = *(const float4*)r0, a1 = *(const float4*)(r0 + 4);
      float4 c0 = *(const float4*)(r0 + Hn), c1 = *(const float4*)(r0 + Hn + 4);
      wx[p][0] = (v2f){a0.x, c0.x}; wx[p][1] = (v2f){a0.y, c0.y};
      wx[p][2] = (v2f){a0.z, c0.z}; wx[p][3] = (v2f){a0.w, c0.w};
      wx[p][4] = (v2f){a1.x, c1.x}; wx[p][5] = (v2f){a1.y, c1.y};
      wx[p][6] = (v2f){a1.z, c1.z}; wx[p][7] = (v2f){a1.w, c1.w};
    }
    const float bj = b1[jcol];
    const int sidx = (jcol >> 5) * HSL + (jcol & 31);
    const int rbase = (ks >> 1) * HSL + ((ks & 1) << 4);

    for (int i = tid; i < 2 * 8 * HSL; i += 512) hc0[i] = 0.f;
    *(float4*)&xs0[4 * tid] = *(const float4*)(xb + 4 * tid);
    __syncthreads();

    float hreg[8];
    float4 xr = make_float4(0.f, 0.f, 0.f, 0.f);
    for (int t8 = 0; t8 < 128; ++t8) {
      const int xcur = (t8 >> 2) & 1;
      #pragma unroll
      for (int s = 0; s < 8; ++s) {
        const int t = t8 * 8 + s;
        const int cu = s & 1, nx = cu ^ 1;
        if (s == 0 && (t8 & 3) == 0 && t8 < 124)
          xr = *(const float4*)(xb + (size_t)((t8 >> 2) + 1) * 2048 + 4 * tid);

        v2f a0 = (v2f){0.f, 0.f}, a1 = a0, a2 = a0, a3 = a0,
            a4 = a0, a5 = a0, a6 = a0, a7 = a0;
        const float4* h4 = (const float4*)&hc0[cu * 8 * HSL + rbase];
        #pragma unroll
        for (int qq = 0; qq < 4; ++qq) {
          float4 hv = h4[qq];
          v2f hA = (v2f){hv.x, hv.y}, hB = (v2f){hv.z, hv.w};
          a0 = __builtin_elementwise_fma(hA, wh[2*qq][0], a0);
          a1 = __builtin_elementwise_fma(hA, wh[2*qq][1], a1);
          a2 = __builtin_elementwise_fma(hA, wh[2*qq][2], a2);
          a3 = __builtin_elementwise_fma(hA, wh[2*qq][3], a3);
          a4 = __builtin_elementwise_fma(hA, wh[2*qq][4], a4);
          a5 = __builtin_elementwise_fma(hA, wh[2*qq][5], a5);
          a6 = __builtin_elementwise_fma(hA, wh[2*qq][6], a6);
          a7 = __builtin_elementwise_fma(hA, wh[2*qq][7], a7);
          a0 = __builtin_elementwise_fma(hB, wh[2*qq+1][0], a0);
          a1 = __builtin_elementwise_fma(hB, wh[2*qq+1][1], a1);
          a2 = __builtin_elementwise_fma(hB, wh[2*qq+1][2], a2);
          a3 = __builtin_elementwise_fma(hB, wh[2*qq+1][3], a3);
          a4 = __builtin_elementwise_fma(hB, wh[2*qq+1][4], a4);
          a5 = __builtin_elementwise_fma(hB, wh[2*qq+1][5], a5);
          a6 = __builtin_elementwise_fma(hB, wh[2*qq+1][6], a6);
          a7 = __builtin_elementwise_fma(hB, wh[2*qq+1][7], a7);
        }
        {
          float4 xv = *(const float4*)&xs0[xcur * 2048 + ((t & 31) << 6) + 4 * ks];
          v2f xA = (v2f){xv.x, xv.y}, xB = (v2f){xv.z, xv.w};
          a0 = __builtin_elementwise_fma(xA, wx[0][0], a0);
          a1 = __builtin_elementwise_fma(xA, wx[0][1], a1);
          a2 = __builtin_elementwise_fma(xA, wx[0][2], a2);
          a3 = __builtin_elementwise_fma(xA, wx[0][3], a3);
          a4 = __builtin_elementwise_fma(xA, wx[0][4], a4);
          a5 = __builtin_elementwise_fma(xA, wx[0][5], a5);
          a6 = __builtin_elementwise_fma(xA, wx[0][6], a6);
          a7 = __builtin_elementwise_fma(xA, wx[0][7], a7);
          a0 = __builtin_elementwise_fma(xB, wx[1][0], a0);
          a1 = __builtin_elementwise_fma(xB, wx[1][1], a1);
          a2 = __builtin_elementwise_fma(xB, wx[1][2], a2);
          a3 = __builtin_elementwise_fma(xB, wx[1][3], a3);
          a4 = __builtin_elementwise_fma(xB, wx[1][4], a4);
          a5 = __builtin_elementwise_fma(xB, wx[1][5], a5);
          a6 = __builtin_elementwise_fma(xB, wx[1][6], a6);
          a7 = __builtin_elementwise_fma(xB, wx[1][7], a7);
        }
        float s0 = row16_sum(a0.x + a0.y), s1 = row16_sum(a1.x + a1.y);
        float s2 = row16_sum(a2.x + a2.y), s3 = row16_sum(a3.x + a3.y);
        float s4 = row16_sum(a4.x + a4.y), s5 = row16_sum(a5.x + a5.y);
        float s6 = row16_sum(a6.x + a6.y), s7 = row16_sum(a7.x + a7.y);
        float h = fast_tanh(sel8(ks, s0, s1, s2, s3, s4, s5, s6, s7) + bj);
        if (writer) hc0[nx * 8 * HSL + sidx] = h;
        hreg[s] = h;
        if (s == 7) {
          if (writer) {
            float* dst = hb + (size_t)(t - 7) * Hn + jcol;
            #pragma unroll
            for (int i = 0; i < 8; ++i) dst[i * Hn] = hreg[i];
          }
          if ((t8 & 3) == 3 && t8 < 127) *(float4*)&xs0[(xcur ^ 1) * 2048 + 4 * tid] = xr;
        }
        __syncthreads();  // vmcnt(0) drained -> safe to release
        if (s == 7 && (t8 & 3) == 3 && tid == 0)
          __hip_atomic_store(flagsA + b, (t8 >> 2) + 1, __ATOMIC_RELEASE,
                             __HIP_MEMORY_SCOPE_AGENT);
      }
    }
  } else if (blockIdx.x < 2 * Bn) {
    // ================= ROLE B: u2 consumer =================
    const int b = blockIdx.x - Bn;
    float* ub = h1buf + (size_t)b * Tn * Hn;  // read h1, overwrite with u2
    float* hs = smem;                          // [32][8*HSL]

    v2f w2[8][8];
    #pragma unroll
    for (int p = 0; p < 8; ++p) {
      const float* r0 = Wx2 + (size_t)(16 * ks + 2 * p) * Hn + col0;
      float4 a0 = *(const float4*)r0, a1 = *(const float4*)(r0 + 4);
      float4 c0 = *(const float4*)(r0 + Hn), c1 = *(const float4*)(r0 + Hn + 4);
      w2[p][0] = (v2f){a0.x, c0.x}; w2[p][1] = (v2f){a0.y, c0.y};
      w2[p][2] = (v2f){a0.z, c0.z}; w2[p][3] = (v2f){a0.w, c0.w};
      w2[p][4] = (v2f){a1.x, c1.x}; w2[p][5] = (v2f){a1.y, c1.y};
      w2[p][6] = (v2f){a1.z, c1.z}; w2[p][7] = (v2f){a1.w, c1.w};
    }
    const float b2j = b2[jcol];
    const int rbase = (ks >> 1) * HSL + ((ks & 1) << 4);
    const int lr = tid >> 4;
    const int lcb = (tid & 15) * 16;
    const int ldst = lr * 8 * HSL + (lcb >> 5) * HSL + (lcb & 31);

    float ureg[8];
    for (int blk = 0; blk < 32; ++blk) {
      if (tid == 0) {
        while (__hip_atomic_load(flagsA + b, __ATOMIC_ACQUIRE,
                                 __HIP_MEMORY_SCOPE_AGENT) < blk + 1)
          __builtin_amdgcn_s_sleep(8);
      }
      __syncthreads();
      {
        const float* src = ub + (size_t)(blk * 32 + lr) * Hn + lcb;
        float4 v0 = ((const float4*)src)[0];
        float4 v1 = ((const float4*)src)[1];
        float4 v2 = ((const float4*)src)[2];
        float4 v3 = ((const float4*)src)[3];
        *(float4*)&hs[ldst + 0] = v0;
        *(float4*)&hs[ldst + 4] = v1;
        *(float4*)&hs[ldst + 8] = v2;
        *(float4*)&hs[ldst + 12] = v3;
      }
      __syncthreads();
      for (int s = 0; s < 32; ++s) {
        v2f a0 = (v2f){0.f, 0.f}, a1 = a0, a2 = a0, a3 = a0,
            a4 = a0, a5 = a0, a6 = a0, a7 = a0;
        const float4* h4 = (const float4*)&hs[s * 8 * HSL + rbase];
        #pragma unroll
        for (int qq = 0; qq < 4; ++qq) {
          float4 hv = h4[qq];
          v2f hA = (v2f){hv.x, hv.y}, hB = (v2f){hv.z, hv.w};
          a0 = __builtin_elementwise_fma(hA, w2[2*qq][0], a0);
          a1 = __builtin_elementwise_fma(hA, w2[2*qq][1], a1);
          a2 = __builtin_elementwise_fma(hA, w2[2*qq][2], a2);
          a3 = __builtin_elementwise_fma(hA, w2[2*qq][3], a3);
          a4 = __builtin_elementwise_fma(hA, w2[2*qq][4], a4);
          a5 = __builtin_elementwise_fma(hA, w2[2*qq][5], a5);
          a6 = __builtin_elementwise_fma(hA, w2[2*qq][6], a6);
          a7 = __builtin_elementwise_fma(hA, w2[2*qq][7], a7);
          a0 = __builtin_elementwise_fma(hB, w2[2*qq+1][0], a0);
          a1 = __builtin_elementwise_fma(hB, w2[2*qq+1][1], a1);
          a2 = __builtin_elementwise_fma(hB, w2[2*qq+1][2], a2);
          a3 = __builtin_elementwise_fma(hB, w2[2*qq+1][3], a3);
          a4 = __builtin_elementwise_fma(hB, w2[2*qq+1][4], a4);
          a5 = __builtin_elementwise_fma(hB, w2[2*qq+1][5], a5);
          a6 = __builtin_elementwise_fma(hB, w2[2*qq+1][6], a6);
          a7 = __builtin_elementwise_fma(hB, w2[2*qq+1][7], a7);
        }
        float s0 = row16_sum(a0.x + a0.y), s1 = row16_sum(a1.x + a1.y);
        float s2 = row16_sum(a2.x + a2.y), s3 = row16_sum(a3.x + a3.y);
        float s4 = row16_sum(a4.x + a4.y), s5 = row16_sum(a5.x + a5.y);
        float s6 = row16_sum(a6.x + a6.y), s7 = row16_sum(a7.x + a7.y);
        ureg[s & 7] = sel8(ks, s0, s1, s2, s3, s4, s5, s6, s7) + b2j;
        if ((s & 7) == 7 && writer) {
          float* dst = ub + (size_t)(blk * 32 + s - 7) * Hn + jcol;
          #pragma unroll
          for (int i = 0; i < 8; ++i) dst[i * Hn] = ureg[i];
        }
      }
      __syncthreads();  // drains u2 stores (vmcnt(0) before s_barrier) + hs reuse
      if (tid == 0)
        __hip_atomic_store(flagsB + b, blk + 1, __ATOMIC_RELEASE,
                           __HIP_MEMORY_SCOPE_AGENT);
    }
  } else {
    // ================= ROLE C: scan2 consumer =================
    const int b = blockIdx.x - 2 * Bn;
    const float* Ub = h1buf + (size_t)b * Tn * Hn;  // u2 (published by role B)
    float* hc0 = smem;  // [2][8*HSL]

    v2f wh[8][8];
    #pragma unroll
    for (int p = 0; p < 8; ++p) {
      const float* r0 = Wh2 + (size_t)(16 * ks + 2 * p) * Hn + col0;
      float4 a0 = *(const float4*)r0, a1 = *(const float4*)(r0 + 4);
      float4 c0 = *(const float4*)(r0 + Hn), c1 = *(const float4*)(r0 + Hn + 4);
      wh[p][0] = (v2f){a0.x, c0.x}; wh[p][1] = (v2f){a0.y, c0.y};
      wh[p][2] = (v2f){a0.z, c0.z}; wh[p][3] = (v2f){a0.w, c0.w};
      wh[p][4] = (v2f){a1.x, c1.x}; wh[p][5] = (v2f){a1.y, c1.y};
      wh[p][6] = (v2f){a1.z, c1.z}; wh[p][7] = (v2f){a1.w, c1.w};
    }
    const int sidx = (jcol >> 5) * HSL + (jcol & 31);
    const int rbase = (ks >> 1) * HSL + ((ks & 1) << 4);

    for (int i = tid; i < 2 * 8 * HSL; i += 512) hc0[i] = 0.f;
    __syncthreads();

    float ucur[8], unxt[8];
    for (int blk = 0; blk < 32; ++blk) {
      if (tid == 0) {
        while (__hip_atomic_load(flagsB + b, __ATOMIC_ACQUIRE,
                                 __HIP_MEMORY_SCOPE_AGENT) < blk + 1)
          __builtin_amdgcn_s_sleep(8);
      }
      __syncthreads();
      if (writer) {
        #pragma unroll
        for (int i = 0; i < 8; ++i)
          ucur[i] = Ub[(size_t)(blk * 32 + i) * Hn + jcol];
      }
      for (int g = 0; g < 4; ++g) {
        if (writer && g < 3) {
          #pragma unroll
          for (int i = 0; i < 8; ++i)
            unxt[i] = Ub[(size_t)(blk * 32 + (g + 1) * 8 + i) * Hn + jcol];
        }
        #pragma unroll
        for (int s = 0; s < 8; ++s) {
          const int cu = s & 1, nx = cu ^ 1;
          v2f a0 = (v2f){0.f, 0.f}, a1 = a0, a2 = a0, a3 = a0,
              a4 = a0, a5 = a0, a6 = a0, a7 = a0;
          const float4* h4 = (const float4*)&hc0[cu * 8 * HSL + rbase];
          #pragma unroll
          for (int qq = 0; qq < 4; ++qq) {
            float4 hv = h4[qq];
            v2f hA = (v2f){hv.x, hv.y}, hB = (v2f){hv.z, hv.w};
            a0 = __builtin_elementwise_fma(hA, wh[2*qq][0], a0);
            a1 = __builtin_elementwise_fma(hA, wh[2*qq][1], a1);
            a2 = __builtin_elementwise_fma(hA, wh[2*qq][2], a2);
            a3 = __builtin_elementwise_fma(hA, wh[2*qq][3], a3);
            a4 = __builtin_elementwise_fma(hA, wh[2*qq][4], a4);
            a5 = __builtin_elementwise_fma(hA, wh[2*qq][5], a5);
            a6 = __builtin_elementwise_fma(hA, wh[2*qq][6], a6);
            a7 = __builtin_elementwise_fma(hA, wh[2*qq][7], a7);
            a0 = __builtin_elementwise_fma(hB, wh[2*qq+1][0], a0);
            a1 = __builtin_elementwise_fma(hB, wh[2*qq+1][1], a1);
            a2 = __builtin_elementwise_fma(hB, wh[2*qq+1][2], a2);
            a3 = __builtin_elementwise_fma(hB, wh[2*qq+1][3], a3);
            a4 = __builtin_elementwise_fma(hB, wh[2*qq+1][4], a4);
            a5 = __builtin_elementwise_fma(hB, wh[2*qq+1][5], a5);
            a6 = __builtin_elementwise_fma(hB, wh[2*qq+1][6], a6);
            a7 = __builtin_elementwise_fma(hB, wh[2*qq+1][7], a7);
          }
          float s0 = row16_sum(a0.x + a0.y), s1 = row16_sum(a1.x + a1.y);
          float s2 = row16_sum(a2.x + a2.y), s3 = row16_sum(a3.x + a3.y);
          float s4 = row16_sum(a4.x + a4.y), s5 = row16_sum(a5.x + a5.y);
          float s6 = row16_sum(a6.x + a6.y), s7 = row16_sum(a7.x + a7.y);
          float h = fast_tanh(sel8(ks, s0, s1, s2, s3, s4, s5, s6, s7) + ucur[s]);
          if (writer) hc0[nx * 8 * HSL + sidx] = h;
          __syncthreads();
        }
        if (writer && g < 3) {
          #pragma unroll
          for (int i = 0; i < 8; ++i) ucur[i] = unxt[i];
        }
      }
    }
    // t=1023: nx=0 -> final h2 in hc0[0]
    if (tid < Hn)
      hfinal[(size_t)b * Hn + tid] = hc0[(tid >> 5) * HSL + (tid & 31)];
  }
}

// ---------------------------------------------------------------------------
// Head: out = softmax(h2_T @ Wd + bd). Unchanged.
// ---------------------------------------------------------------------------
__global__ __launch_bounds__(128) void head_kernel(
    const float* __restrict__ hfinal, const float* __restrict__ Wd,
    const float* __restrict__ bd, float* __restrict__ out) {
  __shared__ float hrow[Hn];
  __shared__ float red[On];
  const int o = threadIdx.x;
  const int b = blockIdx.x;
  hrow[o] = hfinal[(size_t)b * Hn + o];
  hrow[o + 128] = hfinal[(size_t)b * Hn + 128 + o];
  __syncthreads();
  float acc = bd[o];
  #pragma unroll 8
  for (int k = 0; k < Hn; ++k) acc = fmaf(hrow[k], Wd[(size_t)k * On + o], acc);
  red[o] = acc;
  __syncthreads();
  #pragma unroll
  for (int s = 64; s > 0; s >>= 1) {
    if (o < s) red[o] = fmaxf(red[o], red[o + s]);
    __syncthreads();
  }
  const float mx = red[0];
  __syncthreads();
  const float e = __expf(acc - mx);
  red[o] = e;
  __syncthreads();
  #pragma unroll
  for (int s = 64; s > 0; s >>= 1) {
    if (o < s) red[o] += red[o + s];
    __syncthreads();
  }
  out[(size_t)b * On + o] = e / red[0];
}

// ---------------------------------------------------------------------------
extern "C" void kernel_launch(void* const* d_in, const int* in_sizes, int n_in,
                              void* d_out, int out_size, void* d_ws, size_t ws_size,
                              hipStream_t stream) {
  const float* x   = (const float*)d_in[0];
  const float* Wx1 = (const float*)d_in[1];
  const float* Wh1 = (const float*)d_in[2];
  const float* b1  = (const float*)d_in[3];
  const float* Wx2 = (const float*)d_in[4];
  const float* Wh2 = (const float*)d_in[5];
  const float* b2  = (const float*)d_in[6];
  const float* Wd  = (const float*)d_in[7];
  const float* bd  = (const float*)d_in[8];
  float* out = (float*)d_out;

  float* buf = (float*)d_ws;                      // h1 -> (in-place) u2
  float* hfinal = buf + (size_t)Bn * Tn * Hn;     // [B*256]
  int* flagsA = (int*)(hfinal + (size_t)Bn * Hn); // [B]
  int* flagsB = flagsA + Bn;                      // [B]

  hipMemsetAsync(flagsA, 0, 2 * Bn * sizeof(int), stream);
  stage1_kernel<<<3 * Bn, 512, 0, stream>>>(x, Wx1, Wh1, b1, Wx2, b2, Wh2,
                                            buf, hfinal, flagsA, flagsB);
  head_kernel<<<Bn, 128, 0, stream>>>(hfinal, Wd, bd, out);
}

// Round 9
// 1559.685 us; speedup vs baseline: 1.0020x; 1.0020x over previous
//
#include <hip/hip_runtime.h>
#include <cstdint>

constexpr int Bn = 128, Tn = 1024, Dn = 64, Hn = 256, On = 128;
constexpr int HSL = 36;  // padded LDS slice stride (32 data + 4 pad)

typedef float v2f __attribute__((ext_vector_type(2)));

__device__ __forceinline__ float fast_tanh(float x) {
  float e = __expf(2.0f * x);
  return 1.0f - 2.0f / (e + 1.0f);
}

template <int CTRL>
__device__ __forceinline__ float dpp_add(float v) {
  int s = __builtin_amdgcn_update_dpp(0, __float_as_int(v), CTRL, 0xF, 0xF, true);
  return v + __int_as_float(s);
}
__device__ __forceinline__ float row16_sum(float v) {
  v = dpp_add<0xB1>(v);   // quad_perm xor1
  v = dpp_add<0x4E>(v);   // quad_perm xor2
  v = dpp_add<0x141>(v);  // ROW_HALF_MIRROR == xor4
  v = dpp_add<0x140>(v);  // ROW_MIRROR == xor8
  return v;
}

__device__ __forceinline__ float sel8(int ks, float s0, float s1, float s2,
                                      float s3, float s4, float s5, float s6,
                                      float s7) {
  float u0 = (ks & 1) ? s1 : s0;
  float u1 = (ks & 1) ? s3 : s2;
  float u2 = (ks & 1) ? s5 : s4;
  float u3 = (ks & 1) ? s7 : s6;
  float v0 = (ks & 2) ? u1 : u0;
  float v1 = (ks & 2) ? u3 : u2;
  return (ks & 4) ? v1 : v0;
}

// ---------------------------------------------------------------------------
// 3-stage pipeline, PLACEMENT-AWARE role order (fix for R8 regression):
//   blockIdx [0,128):   role A — scan1 producer          (per-XCD CU slots 0-15)
//   blockIdx [128,256): role C — scan2 consumer of u2    (per-XCD CU slots 16-31)
//   blockIdx [256,384): role B — u2=h1@Wx2+b2 (cheap)    (doubles up on A's CUs)
// Rationale: gfx950 dispatch round-robins blocks across XCDs (i -> XCD i%8),
// CU slot advancing every 8 blocks. R8's order co-located the two LDS-heavy
// scans (A,C) on the same CUs -> LDS-pipe contention, 1616 us. This order
// gives each scan a dedicated CU; B (idle ~85%, waits on A cadence) pairs
// with A — interference already measured at +14% in R7.
// DAG A->B->C via drained-barrier->release / spin-acquire (bit-exact in R7/R8).
// ---------------------------------------------------------------------------
__global__ __launch_bounds__(512, 2) void stage1_kernel(
    const float* __restrict__ x,    // [B,T,64]
    const float* __restrict__ Wx1,  // [64,256]
    const float* __restrict__ Wh1,  // [256,256]
    const float* __restrict__ b1,   // [256]
    const float* __restrict__ Wx2,  // [256,256]
    const float* __restrict__ b2,   // [256]
    const float* __restrict__ Wh2,  // [256,256]
    float* __restrict__ h1buf,      // [B,T,256] h1 then (in-place) u2
    float* __restrict__ hfinal,     // [B,256]
    int* __restrict__ flagsA,       // [B]
    int* __restrict__ flagsB) {     // [B]
  __shared__ alignas(16) float smem[32 * 8 * HSL];  // 36.9 KB union of roles
  const int tid = threadIdx.x;
  const int ks = tid & 15;
  const int cg = tid >> 4;
  const int col0 = 8 * cg;
  const int jcol = col0 + (ks & 7);
  const bool writer = (ks < 8);

  if (blockIdx.x < Bn) {
    // ================= ROLE A: scan1 producer =================
    const int b = blockIdx.x;
    const float* xb = x + (size_t)b * Tn * Dn;
    float* hb = h1buf + (size_t)b * Tn * Hn;
    float* hc0 = smem;          // [2][8*HSL]
    float* xs0 = smem + 576;    // [2][2048]

    v2f wh[8][8];
    #pragma unroll
    for (int p = 0; p < 8; ++p) {
      const float* r0 = Wh1 + (size_t)(16 * ks + 2 * p) * Hn + col0;
      float4 a0 = *(const float4*)r0, a1 = *(const float4*)(r0 + 4);
      float4 c0 = *(const float4*)(r0 + Hn), c1 = *(const float4*)(r0 + Hn + 4);
      wh[p][0] = (v2f){a0.x, c0.x}; wh[p][1] = (v2f){a0.y, c0.y};
      wh[p][2] = (v2f){a0.z, c0.z}; wh[p][3] = (v2f){a0.w, c0.w};
      wh[p][4] = (v2f){a1.x, c1.x}; wh[p][5] = (v2f){a1.y, c1.y};
      wh[p][6] = (v2f){a1.z, c1.z}; wh[p][7] = (v2f){a1.w, c1.w};
    }
    v2f wx[2][8];
    #pragma unroll
    for (int p = 0; p < 2; ++p) {
      const float* r0 = Wx1 + (size_t)(4 * ks + 2 * p) * Hn + col0;
      float4 a0 = *(const float4*)r0, a1 = *(const float4*)(r0 + 4);
      float4 c0 = *(const float4*)(r0 + Hn), c1 = *(const float4*)(r0 + Hn + 4);
      wx[p][0] = (v2f){a0.x, c0.x}; wx[p][1] = (v2f){a0.y, c0.y};
      wx[p][2] = (v2f){a0.z, c0.z}; wx[p][3] = (v2f){a0.w, c0.w};
      wx[p][4] = (v2f){a1.x, c1.x}; wx[p][5] = (v2f){a1.y, c1.y};
      wx[p][6] = (v2f){a1.z, c1.z}; wx[p][7] = (v2f){a1.w, c1.w};
    }
    const float bj = b1[jcol];
    const int sidx = (jcol >> 5) * HSL + (jcol & 31);
    const int rbase = (ks >> 1) * HSL + ((ks & 1) << 4);

    for (int i = tid; i < 2 * 8 * HSL; i += 512) hc0[i] = 0.f;
    *(float4*)&xs0[4 * tid] = *(const float4*)(xb + 4 * tid);
    __syncthreads();

    float hreg[8];
    float4 xr = make_float4(0.f, 0.f, 0.f, 0.f);
    for (int t8 = 0; t8 < 128; ++t8) {
      const int xcur = (t8 >> 2) & 1;
      #pragma unroll
      for (int s = 0; s < 8; ++s) {
        const int t = t8 * 8 + s;
        const int cu = s & 1, nx = cu ^ 1;
        if (s == 0 && (t8 & 3) == 0 && t8 < 124)
          xr = *(const float4*)(xb + (size_t)((t8 >> 2) + 1) * 2048 + 4 * tid);

        v2f a0 = (v2f){0.f, 0.f}, a1 = a0, a2 = a0, a3 = a0,
            a4 = a0, a5 = a0, a6 = a0, a7 = a0;
        const float4* h4 = (const float4*)&hc0[cu * 8 * HSL + rbase];
        #pragma unroll
        for (int qq = 0; qq < 4; ++qq) {
          float4 hv = h4[qq];
          v2f hA = (v2f){hv.x, hv.y}, hB = (v2f){hv.z, hv.w};
          a0 = __builtin_elementwise_fma(hA, wh[2*qq][0], a0);
          a1 = __builtin_elementwise_fma(hA, wh[2*qq][1], a1);
          a2 = __builtin_elementwise_fma(hA, wh[2*qq][2], a2);
          a3 = __builtin_elementwise_fma(hA, wh[2*qq][3], a3);
          a4 = __builtin_elementwise_fma(hA, wh[2*qq][4], a4);
          a5 = __builtin_elementwise_fma(hA, wh[2*qq][5], a5);
          a6 = __builtin_elementwise_fma(hA, wh[2*qq][6], a6);
          a7 = __builtin_elementwise_fma(hA, wh[2*qq][7], a7);
          a0 = __builtin_elementwise_fma(hB, wh[2*qq+1][0], a0);
          a1 = __builtin_elementwise_fma(hB, wh[2*qq+1][1], a1);
          a2 = __builtin_elementwise_fma(hB, wh[2*qq+1][2], a2);
          a3 = __builtin_elementwise_fma(hB, wh[2*qq+1][3], a3);
          a4 = __builtin_elementwise_fma(hB, wh[2*qq+1][4], a4);
          a5 = __builtin_elementwise_fma(hB, wh[2*qq+1][5], a5);
          a6 = __builtin_elementwise_fma(hB, wh[2*qq+1][6], a6);
          a7 = __builtin_elementwise_fma(hB, wh[2*qq+1][7], a7);
        }
        {
          float4 xv = *(const float4*)&xs0[xcur * 2048 + ((t & 31) << 6) + 4 * ks];
          v2f xA = (v2f){xv.x, xv.y}, xB = (v2f){xv.z, xv.w};
          a0 = __builtin_elementwise_fma(xA, wx[0][0], a0);
          a1 = __builtin_elementwise_fma(xA, wx[0][1], a1);
          a2 = __builtin_elementwise_fma(xA, wx[0][2], a2);
          a3 = __builtin_elementwise_fma(xA, wx[0][3], a3);
          a4 = __builtin_elementwise_fma(xA, wx[0][4], a4);
          a5 = __builtin_elementwise_fma(xA, wx[0][5], a5);
          a6 = __builtin_elementwise_fma(xA, wx[0][6], a6);
          a7 = __builtin_elementwise_fma(xA, wx[0][7], a7);
          a0 = __builtin_elementwise_fma(xB, wx[1][0], a0);
          a1 = __builtin_elementwise_fma(xB, wx[1][1], a1);
          a2 = __builtin_elementwise_fma(xB, wx[1][2], a2);
          a3 = __builtin_elementwise_fma(xB, wx[1][3], a3);
          a4 = __builtin_elementwise_fma(xB, wx[1][4], a4);
          a5 = __builtin_elementwise_fma(xB, wx[1][5], a5);
          a6 = __builtin_elementwise_fma(xB, wx[1][6], a6);
          a7 = __builtin_elementwise_fma(xB, wx[1][7], a7);
        }
        float s0 = row16_sum(a0.x + a0.y), s1 = row16_sum(a1.x + a1.y);
        float s2 = row16_sum(a2.x + a2.y), s3 = row16_sum(a3.x + a3.y);
        float s4 = row16_sum(a4.x + a4.y), s5 = row16_sum(a5.x + a5.y);
        float s6 = row16_sum(a6.x + a6.y), s7 = row16_sum(a7.x + a7.y);
        float h = fast_tanh(sel8(ks, s0, s1, s2, s3, s4, s5, s6, s7) + bj);
        if (writer) hc0[nx * 8 * HSL + sidx] = h;
        hreg[s] = h;
        if (s == 7) {
          if (writer) {
            float* dst = hb + (size_t)(t - 7) * Hn + jcol;
            #pragma unroll
            for (int i = 0; i < 8; ++i) dst[i * Hn] = hreg[i];
          }
          if ((t8 & 3) == 3 && t8 < 127) *(float4*)&xs0[(xcur ^ 1) * 2048 + 4 * tid] = xr;
        }
        __syncthreads();  // vmcnt(0) drained -> safe to release
        if (s == 7 && (t8 & 3) == 3 && tid == 0)
          __hip_atomic_store(flagsA + b, (t8 >> 2) + 1, __ATOMIC_RELEASE,
                             __HIP_MEMORY_SCOPE_AGENT);
      }
    }
  } else if (blockIdx.x < 2 * Bn) {
    // ================= ROLE C: scan2 consumer =================
    const int b = blockIdx.x - Bn;
    const float* Ub = h1buf + (size_t)b * Tn * Hn;  // u2 (published by role B)
    float* hc0 = smem;  // [2][8*HSL]

    v2f wh[8][8];
    #pragma unroll
    for (int p = 0; p < 8; ++p) {
      const float* r0 = Wh2 + (size_t)(16 * ks + 2 * p) * Hn + col0;
      float4 a0 = *(const float4*)r0, a1 = *(const float4*)(r0 + 4);
      float4 c0 = *(const float4*)(r0 + Hn), c1 = *(const float4*)(r0 + Hn + 4);
      wh[p][0] = (v2f){a0.x, c0.x}; wh[p][1] = (v2f){a0.y, c0.y};
      wh[p][2] = (v2f){a0.z, c0.z}; wh[p][3] = (v2f){a0.w, c0.w};
      wh[p][4] = (v2f){a1.x, c1.x}; wh[p][5] = (v2f){a1.y, c1.y};
      wh[p][6] = (v2f){a1.z, c1.z}; wh[p][7] = (v2f){a1.w, c1.w};
    }
    const int sidx = (jcol >> 5) * HSL + (jcol & 31);
    const int rbase = (ks >> 1) * HSL + ((ks & 1) << 4);

    for (int i = tid; i < 2 * 8 * HSL; i += 512) hc0[i] = 0.f;
    __syncthreads();

    float ucur[8], unxt[8];
    for (int blk = 0; blk < 32; ++blk) {
      if (tid == 0) {
        while (__hip_atomic_load(flagsB + b, __ATOMIC_ACQUIRE,
                                 __HIP_MEMORY_SCOPE_AGENT) < blk + 1)
          __builtin_amdgcn_s_sleep(8);
      }
      __syncthreads();
      if (writer) {
        #pragma unroll
        for (int i = 0; i < 8; ++i)
          ucur[i] = Ub[(size_t)(blk * 32 + i) * Hn + jcol];
      }
      for (int g = 0; g < 4; ++g) {
        if (writer && g < 3) {
          #pragma unroll
          for (int i = 0; i < 8; ++i)
            unxt[i] = Ub[(size_t)(blk * 32 + (g + 1) * 8 + i) * Hn + jcol];
        }
        #pragma unroll
        for (int s = 0; s < 8; ++s) {
          const int cu = s & 1, nx = cu ^ 1;
          v2f a0 = (v2f){0.f, 0.f}, a1 = a0, a2 = a0, a3 = a0,
              a4 = a0, a5 = a0, a6 = a0, a7 = a0;
          const float4* h4 = (const float4*)&hc0[cu * 8 * HSL + rbase];
          #pragma unroll
          for (int qq = 0; qq < 4; ++qq) {
            float4 hv = h4[qq];
            v2f hA = (v2f){hv.x, hv.y}, hB = (v2f){hv.z, hv.w};
            a0 = __builtin_elementwise_fma(hA, wh[2*qq][0], a0);
            a1 = __builtin_elementwise_fma(hA, wh[2*qq][1], a1);
            a2 = __builtin_elementwise_fma(hA, wh[2*qq][2], a2);
            a3 = __builtin_elementwise_fma(hA, wh[2*qq][3], a3);
            a4 = __builtin_elementwise_fma(hA, wh[2*qq][4], a4);
            a5 = __builtin_elementwise_fma(hA, wh[2*qq][5], a5);
            a6 = __builtin_elementwise_fma(hA, wh[2*qq][6], a6);
            a7 = __builtin_elementwise_fma(hA, wh[2*qq][7], a7);
            a0 = __builtin_elementwise_fma(hB, wh[2*qq+1][0], a0);
            a1 = __builtin_elementwise_fma(hB, wh[2*qq+1][1], a1);
            a2 = __builtin_elementwise_fma(hB, wh[2*qq+1][2], a2);
            a3 = __builtin_elementwise_fma(hB, wh[2*qq+1][3], a3);
            a4 = __builtin_elementwise_fma(hB, wh[2*qq+1][4], a4);
            a5 = __builtin_elementwise_fma(hB, wh[2*qq+1][5], a5);
            a6 = __builtin_elementwise_fma(hB, wh[2*qq+1][6], a6);
            a7 = __builtin_elementwise_fma(hB, wh[2*qq+1][7], a7);
          }
          float s0 = row16_sum(a0.x + a0.y), s1 = row16_sum(a1.x + a1.y);
          float s2 = row16_sum(a2.x + a2.y), s3 = row16_sum(a3.x + a3.y);
          float s4 = row16_sum(a4.x + a4.y), s5 = row16_sum(a5.x + a5.y);
          float s6 = row16_sum(a6.x + a6.y), s7 = row16_sum(a7.x + a7.y);
          float h = fast_tanh(sel8(ks, s0, s1, s2, s3, s4, s5, s6, s7) + ucur[s]);
          if (writer) hc0[nx * 8 * HSL + sidx] = h;
          __syncthreads();
        }
        if (writer && g < 3) {
          #pragma unroll
          for (int i = 0; i < 8; ++i) ucur[i] = unxt[i];
        }
      }
    }
    // t=1023: nx=0 -> final h2 in hc0[0]
    if (tid < Hn)
      hfinal[(size_t)b * Hn + tid] = hc0[(tid >> 5) * HSL + (tid & 31)];
  } else {
    // ================= ROLE B: u2 consumer/producer =================
    const int b = blockIdx.x - 2 * Bn;
    float* ub = h1buf + (size_t)b * Tn * Hn;  // read h1, overwrite with u2
    float* hs = smem;                          // [32][8*HSL]

    v2f w2[8][8];
    #pragma unroll
    for (int p = 0; p < 8; ++p) {
      const float* r0 = Wx2 + (size_t)(16 * ks + 2 * p) * Hn + col0;
      float4 a0 = *(const float4*)r0, a1 = *(const float4*)(r0 + 4);
      float4 c0 = *(const float4*)(r0 + Hn), c1 = *(const float4*)(r0 + Hn + 4);
      w2[p][0] = (v2f){a0.x, c0.x}; w2[p][1] = (v2f){a0.y, c0.y};
      w2[p][2] = (v2f){a0.z, c0.z}; w2[p][3] = (v2f){a0.w, c0.w};
      w2[p][4] = (v2f){a1.x, c1.x}; w2[p][5] = (v2f){a1.y, c1.y};
      w2[p][6] = (v2f){a1.z, c1.z}; w2[p][7] = (v2f){a1.w, c1.w};
    }
    const float b2j = b2[jcol];
    const int rbase = (ks >> 1) * HSL + ((ks & 1) << 4);
    const int lr = tid >> 4;
    const int lcb = (tid & 15) * 16;
    const int ldst = lr * 8 * HSL + (lcb >> 5) * HSL + (lcb & 31);

    float ureg[8];
    for (int blk = 0; blk < 32; ++blk) {
      if (tid == 0) {
        while (__hip_atomic_load(flagsA + b, __ATOMIC_ACQUIRE,
                                 __HIP_MEMORY_SCOPE_AGENT) < blk + 1)
          __builtin_amdgcn_s_sleep(8);
      }
      __syncthreads();
      {
        const float* src = ub + (size_t)(blk * 32 + lr) * Hn + lcb;
        float4 v0 = ((const float4*)src)[0];
        float4 v1 = ((const float4*)src)[1];
        float4 v2 = ((const float4*)src)[2];
        float4 v3 = ((const float4*)src)[3];
        *(float4*)&hs[ldst + 0] = v0;
        *(float4*)&hs[ldst + 4] = v1;
        *(float4*)&hs[ldst + 8] = v2;
        *(float4*)&hs[ldst + 12] = v3;
      }
      __syncthreads();
      for (int s = 0; s < 32; ++s) {
        v2f a0 = (v2f){0.f, 0.f}, a1 = a0, a2 = a0, a3 = a0,
            a4 = a0, a5 = a0, a6 = a0, a7 = a0;
        const float4* h4 = (const float4*)&hs[s * 8 * HSL + rbase];
        #pragma unroll
        for (int qq = 0; qq < 4; ++qq) {
          float4 hv = h4[qq];
          v2f hA = (v2f){hv.x, hv.y}, hB = (v2f){hv.z, hv.w};
          a0 = __builtin_elementwise_fma(hA, w2[2*qq][0], a0);
          a1 = __builtin_elementwise_fma(hA, w2[2*qq][1], a1);
          a2 = __builtin_elementwise_fma(hA, w2[2*qq][2], a2);
          a3 = __builtin_elementwise_fma(hA, w2[2*qq][3], a3);
          a4 = __builtin_elementwise_fma(hA, w2[2*qq][4], a4);
          a5 = __builtin_elementwise_fma(hA, w2[2*qq][5], a5);
          a6 = __builtin_elementwise_fma(hA, w2[2*qq][6], a6);
          a7 = __builtin_elementwise_fma(hA, w2[2*qq][7], a7);
          a0 = __builtin_elementwise_fma(hB, w2[2*qq+1][0], a0);
          a1 = __builtin_elementwise_fma(hB, w2[2*qq+1][1], a1);
          a2 = __builtin_elementwise_fma(hB, w2[2*qq+1][2], a2);
          a3 = __builtin_elementwise_fma(hB, w2[2*qq+1][3], a3);
          a4 = __builtin_elementwise_fma(hB, w2[2*qq+1][4], a4);
          a5 = __builtin_elementwise_fma(hB, w2[2*qq+1][5], a5);
          a6 = __builtin_elementwise_fma(hB, w2[2*qq+1][6], a6);
          a7 = __builtin_elementwise_fma(hB, w2[2*qq+1][7], a7);
        }
        float s0 = row16_sum(a0.x + a0.y), s1 = row16_sum(a1.x + a1.y);
        float s2 = row16_sum(a2.x + a2.y), s3 = row16_sum(a3.x + a3.y);
        float s4 = row16_sum(a4.x + a4.y), s5 = row16_sum(a5.x + a5.y);
        float s6 = row16_sum(a6.x + a6.y), s7 = row16_sum(a7.x + a7.y);
        ureg[s & 7] = sel8(ks, s0, s1, s2, s3, s4, s5, s6, s7) + b2j;
        if ((s & 7) == 7 && writer) {
          float* dst = ub + (size_t)(blk * 32 + s - 7) * Hn + jcol;
          #pragma unroll
          for (int i = 0; i < 8; ++i) dst[i * Hn] = ureg[i];
        }
      }
      __syncthreads();  // drains u2 stores (vmcnt(0) before s_barrier) + hs reuse
      if (tid == 0)
        __hip_atomic_store(flagsB + b, blk + 1, __ATOMIC_RELEASE,
                           __HIP_MEMORY_SCOPE_AGENT);
    }
  }
}

// ---------------------------------------------------------------------------
// Head: out = softmax(h2_T @ Wd + bd). Unchanged.
// ---------------------------------------------------------------------------
__global__ __launch_bounds__(128) void head_kernel(
    const float* __restrict__ hfinal, const float* __restrict__ Wd,
    const float* __restrict__ bd, float* __restrict__ out) {
  __shared__ float hrow[Hn];
  __shared__ float red[On];
  const int o = threadIdx.x;
  const int b = blockIdx.x;
  hrow[o] = hfinal[(size_t)b * Hn + o];
  hrow[o + 128] = hfinal[(size_t)b * Hn + 128 + o];
  __syncthreads();
  float acc = bd[o];
  #pragma unroll 8
  for (int k = 0; k < Hn; ++k) acc = fmaf(hrow[k], Wd[(size_t)k * On + o], acc);
  red[o] = acc;
  __syncthreads();
  #pragma unroll
  for (int s = 64; s > 0; s >>= 1) {
    if (o < s) red[o] = fmaxf(red[o], red[o + s]);
    __syncthreads();
  }
  const float mx = red[0];
  __syncthreads();
  const float e = __expf(acc - mx);
  red[o] = e;
  __syncthreads();
  #pragma unroll
  for (int s = 64; s > 0; s >>= 1) {
    if (o < s) red[o] += red[o + s];
    __syncthreads();
  }
  out[(size_t)b * On + o] = e / red[0];
}

// ---------------------------------------------------------------------------
extern "C" void kernel_launch(void* const* d_in, const int* in_sizes, int n_in,
                              void* d_out, int out_size, void* d_ws, size_t ws_size,
                              hipStream_t stream) {
  const float* x   = (const float*)d_in[0];
  const float* Wx1 = (const float*)d_in[1];
  const float* Wh1 = (const float*)d_in[2];
  const float* b1  = (const float*)d_in[3];
  const float* Wx2 = (const float*)d_in[4];
  const float* Wh2 = (const float*)d_in[5];
  const float* b2  = (const float*)d_in[6];
  const float* Wd  = (const float*)d_in[7];
  const float* bd  = (const float*)d_in[8];
  float* out = (float*)d_out;

  float* buf = (float*)d_ws;                      // h1 -> (in-place) u2
  float* hfinal = buf + (size_t)Bn * Tn * Hn;     // [B*256]
  int* flagsA = (int*)(hfinal + (size_t)Bn * Hn); // [B]
  int* flagsB = flagsA + Bn;                      // [B]

  hipMemsetAsync(flagsA, 0, 2 * Bn * sizeof(int), stream);
  stage1_kernel<<<3 * Bn, 512, 0, stream>>>(x, Wx1, Wh1, b1, Wx2, b2, Wh2,
                                            buf, hfinal, flagsA, flagsB);
  head_kernel<<<Bn, 128, 0, stream>>>(hfinal, Wd, bd, out);
}

// Round 10
// 1528.755 us; speedup vs baseline: 1.0223x; 1.0202x over previous
//
#include <hip/hip_runtime.h>
#include <cstdint>

constexpr int Bn = 128, Tn = 1024, Dn = 64, Hn = 256, On = 128;
constexpr int HSL = 36;  // padded LDS slice stride (32 data + 4 pad)

typedef float v2f __attribute__((ext_vector_type(2)));

__device__ __forceinline__ float fast_tanh(float x) {
  float e = __expf(2.0f * x);
  return 1.0f - 2.0f / (e + 1.0f);
}

// Packed f32 FMA, forced: d.lo=a.lo*b.lo+c.lo, d.hi=a.hi*b.hi+c.hi.
// R6 measured active-CU VALU issue (~1215 cyc/step) matches scalar-fma
// lowering of __builtin_elementwise_fma, not v_pk_fma_f32 — force it.
__device__ __forceinline__ v2f pk_fma(v2f a, v2f b, v2f c) {
  v2f d;
  asm("v_pk_fma_f32 %0, %1, %2, %3" : "=v"(d) : "v"(a), "v"(b), "v"(c));
  return d;
}

template <int CTRL>
__device__ __forceinline__ float dpp_add(float v) {
  int s = __builtin_amdgcn_update_dpp(0, __float_as_int(v), CTRL, 0xF, 0xF, true);
  return v + __int_as_float(s);
}
__device__ __forceinline__ float row16_sum(float v) {
  v = dpp_add<0xB1>(v);   // quad_perm xor1
  v = dpp_add<0x4E>(v);   // quad_perm xor2
  v = dpp_add<0x141>(v);  // ROW_HALF_MIRROR == xor4
  v = dpp_add<0x140>(v);  // ROW_MIRROR == xor8
  return v;
}

__device__ __forceinline__ float sel8(int ks, float s0, float s1, float s2,
                                      float s3, float s4, float s5, float s6,
                                      float s7) {
  float u0 = (ks & 1) ? s1 : s0;
  float u1 = (ks & 1) ? s3 : s2;
  float u2 = (ks & 1) ? s5 : s4;
  float u3 = (ks & 1) ? s7 : s6;
  float v0 = (ks & 2) ? u1 : u0;
  float v1 = (ks & 2) ? u3 : u2;
  return (ks & 4) ? v1 : v0;
}

// ---------------------------------------------------------------------------
// Stage 1 (256 WGs) — R7 structure (best measured: 855 us):
//   WGs [0,128):   role A — scan1 producer, releases flagsA[b]/32-step block
//   WGs [128,256): role B — u2 = h1@Wx2+b2 in place, cheap, tracks A
// R8/R9 proved adding role C regresses (role-order-independent interference);
// scan2 stays a separate kernel.
// ---------------------------------------------------------------------------
__global__ __launch_bounds__(512, 2) void stage1_kernel(
    const float* __restrict__ x,    // [B,T,64]
    const float* __restrict__ Wx1,  // [64,256]
    const float* __restrict__ Wh1,  // [256,256]
    const float* __restrict__ b1,   // [256]
    const float* __restrict__ Wx2,  // [256,256]
    const float* __restrict__ b2,   // [256]
    float* __restrict__ h1buf,      // [B,T,256] h1 then (in-place) u2
    int* __restrict__ flags) {      // [B]
  __shared__ alignas(16) float smem[32 * 8 * HSL];
  const int tid = threadIdx.x;
  const int ks = tid & 15;
  const int cg = tid >> 4;
  const int col0 = 8 * cg;
  const int jcol = col0 + (ks & 7);
  const bool writer = (ks < 8);

  if (blockIdx.x < Bn) {
    // ================= ROLE A: scan1 producer =================
    const int b = blockIdx.x;
    const float* xb = x + (size_t)b * Tn * Dn;
    float* hb = h1buf + (size_t)b * Tn * Hn;
    float* hc0 = smem;          // [2][8*HSL]
    float* xs0 = smem + 576;    // [2][2048]

    v2f wh[8][8];
    #pragma unroll
    for (int p = 0; p < 8; ++p) {
      const float* r0 = Wh1 + (size_t)(16 * ks + 2 * p) * Hn + col0;
      float4 a0 = *(const float4*)r0, a1 = *(const float4*)(r0 + 4);
      float4 c0 = *(const float4*)(r0 + Hn), c1 = *(const float4*)(r0 + Hn + 4);
      wh[p][0] = (v2f){a0.x, c0.x}; wh[p][1] = (v2f){a0.y, c0.y};
      wh[p][2] = (v2f){a0.z, c0.z}; wh[p][3] = (v2f){a0.w, c0.w};
      wh[p][4] = (v2f){a1.x, c1.x}; wh[p][5] = (v2f){a1.y, c1.y};
      wh[p][6] = (v2f){a1.z, c1.z}; wh[p][7] = (v2f){a1.w, c1.w};
    }
    v2f wx[2][8];
    #pragma unroll
    for (int p = 0; p < 2; ++p) {
      const float* r0 = Wx1 + (size_t)(4 * ks + 2 * p) * Hn + col0;
      float4 a0 = *(const float4*)r0, a1 = *(const float4*)(r0 + 4);
      float4 c0 = *(const float4*)(r0 + Hn), c1 = *(const float4*)(r0 + Hn + 4);
      wx[p][0] = (v2f){a0.x, c0.x}; wx[p][1] = (v2f){a0.y, c0.y};
      wx[p][2] = (v2f){a0.z, c0.z}; wx[p][3] = (v2f){a0.w, c0.w};
      wx[p][4] = (v2f){a1.x, c1.x}; wx[p][5] = (v2f){a1.y, c1.y};
      wx[p][6] = (v2f){a1.z, c1.z}; wx[p][7] = (v2f){a1.w, c1.w};
    }
    const float bj = b1[jcol];
    const int sidx = (jcol >> 5) * HSL + (jcol & 31);
    const int rbase = (ks >> 1) * HSL + ((ks & 1) << 4);

    for (int i = tid; i < 2 * 8 * HSL; i += 512) hc0[i] = 0.f;
    *(float4*)&xs0[4 * tid] = *(const float4*)(xb + 4 * tid);
    __syncthreads();

    float hreg[8];
    float4 xr = make_float4(0.f, 0.f, 0.f, 0.f);
    for (int t8 = 0; t8 < 128; ++t8) {
      const int xcur = (t8 >> 2) & 1;
      #pragma unroll
      for (int s = 0; s < 8; ++s) {
        const int t = t8 * 8 + s;
        const int cu = s & 1, nx = cu ^ 1;
        if (s == 0 && (t8 & 3) == 0 && t8 < 124)
          xr = *(const float4*)(xb + (size_t)((t8 >> 2) + 1) * 2048 + 4 * tid);

        v2f a0 = (v2f){0.f, 0.f}, a1 = a0, a2 = a0, a3 = a0,
            a4 = a0, a5 = a0, a6 = a0, a7 = a0;
        const float4* h4 = (const float4*)&hc0[cu * 8 * HSL + rbase];
        #pragma unroll
        for (int qq = 0; qq < 4; ++qq) {
          float4 hv = h4[qq];
          v2f hA = (v2f){hv.x, hv.y}, hB = (v2f){hv.z, hv.w};
          a0 = pk_fma(hA, wh[2*qq][0], a0);
          a1 = pk_fma(hA, wh[2*qq][1], a1);
          a2 = pk_fma(hA, wh[2*qq][2], a2);
          a3 = pk_fma(hA, wh[2*qq][3], a3);
          a4 = pk_fma(hA, wh[2*qq][4], a4);
          a5 = pk_fma(hA, wh[2*qq][5], a5);
          a6 = pk_fma(hA, wh[2*qq][6], a6);
          a7 = pk_fma(hA, wh[2*qq][7], a7);
          a0 = pk_fma(hB, wh[2*qq+1][0], a0);
          a1 = pk_fma(hB, wh[2*qq+1][1], a1);
          a2 = pk_fma(hB, wh[2*qq+1][2], a2);
          a3 = pk_fma(hB, wh[2*qq+1][3], a3);
          a4 = pk_fma(hB, wh[2*qq+1][4], a4);
          a5 = pk_fma(hB, wh[2*qq+1][5], a5);
          a6 = pk_fma(hB, wh[2*qq+1][6], a6);
          a7 = pk_fma(hB, wh[2*qq+1][7], a7);
        }
        {
          float4 xv = *(const float4*)&xs0[xcur * 2048 + ((t & 31) << 6) + 4 * ks];
          v2f xA = (v2f){xv.x, xv.y}, xB = (v2f){xv.z, xv.w};
          a0 = pk_fma(xA, wx[0][0], a0);
          a1 = pk_fma(xA, wx[0][1], a1);
          a2 = pk_fma(xA, wx[0][2], a2);
          a3 = pk_fma(xA, wx[0][3], a3);
          a4 = pk_fma(xA, wx[0][4], a4);
          a5 = pk_fma(xA, wx[0][5], a5);
          a6 = pk_fma(xA, wx[0][6], a6);
          a7 = pk_fma(xA, wx[0][7], a7);
          a0 = pk_fma(xB, wx[1][0], a0);
          a1 = pk_fma(xB, wx[1][1], a1);
          a2 = pk_fma(xB, wx[1][2], a2);
          a3 = pk_fma(xB, wx[1][3], a3);
          a4 = pk_fma(xB, wx[1][4], a4);
          a5 = pk_fma(xB, wx[1][5], a5);
          a6 = pk_fma(xB, wx[1][6], a6);
          a7 = pk_fma(xB, wx[1][7], a7);
        }
        float s0 = row16_sum(a0.x + a0.y), s1 = row16_sum(a1.x + a1.y);
        float s2 = row16_sum(a2.x + a2.y), s3 = row16_sum(a3.x + a3.y);
        float s4 = row16_sum(a4.x + a4.y), s5 = row16_sum(a5.x + a5.y);
        float s6 = row16_sum(a6.x + a6.y), s7 = row16_sum(a7.x + a7.y);
        float h = fast_tanh(sel8(ks, s0, s1, s2, s3, s4, s5, s6, s7) + bj);
        if (writer) hc0[nx * 8 * HSL + sidx] = h;
        hreg[s] = h;
        if (s == 7) {
          if (writer) {
            float* dst = hb + (size_t)(t - 7) * Hn + jcol;
            #pragma unroll
            for (int i = 0; i < 8; ++i) dst[i * Hn] = hreg[i];
          }
          if ((t8 & 3) == 3 && t8 < 127) *(float4*)&xs0[(xcur ^ 1) * 2048 + 4 * tid] = xr;
        }
        __syncthreads();  // vmcnt(0) drained -> safe to release
        if (s == 7 && (t8 & 3) == 3 && tid == 0)
          __hip_atomic_store(flags + b, (t8 >> 2) + 1, __ATOMIC_RELEASE,
                             __HIP_MEMORY_SCOPE_AGENT);
      }
    }
  } else {
    // ================= ROLE B: u2 consumer =================
    const int b = blockIdx.x - Bn;
    float* ub = h1buf + (size_t)b * Tn * Hn;  // read h1, overwrite with u2
    float* hs = smem;                          // [32][8*HSL]

    v2f w2[8][8];
    #pragma unroll
    for (int p = 0; p < 8; ++p) {
      const float* r0 = Wx2 + (size_t)(16 * ks + 2 * p) * Hn + col0;
      float4 a0 = *(const float4*)r0, a1 = *(const float4*)(r0 + 4);
      float4 c0 = *(const float4*)(r0 + Hn), c1 = *(const float4*)(r0 + Hn + 4);
      w2[p][0] = (v2f){a0.x, c0.x}; w2[p][1] = (v2f){a0.y, c0.y};
      w2[p][2] = (v2f){a0.z, c0.z}; w2[p][3] = (v2f){a0.w, c0.w};
      w2[p][4] = (v2f){a1.x, c1.x}; w2[p][5] = (v2f){a1.y, c1.y};
      w2[p][6] = (v2f){a1.z, c1.z}; w2[p][7] = (v2f){a1.w, c1.w};
    }
    const float b2j = b2[jcol];
    const int rbase = (ks >> 1) * HSL + ((ks & 1) << 4);
    const int lr = tid >> 4;
    const int lcb = (tid & 15) * 16;
    const int ldst = lr * 8 * HSL + (lcb >> 5) * HSL + (lcb & 31);

    float ureg[8];
    for (int blk = 0; blk < 32; ++blk) {
      if (tid == 0) {
        while (__hip_atomic_load(flags + b, __ATOMIC_ACQUIRE,
                                 __HIP_MEMORY_SCOPE_AGENT) < blk + 1)
          __builtin_amdgcn_s_sleep(8);
      }
      __syncthreads();
      {
        const float* src = ub + (size_t)(blk * 32 + lr) * Hn + lcb;
        float4 v0 = ((const float4*)src)[0];
        float4 v1 = ((const float4*)src)[1];
        float4 v2 = ((const float4*)src)[2];
        float4 v3 = ((const float4*)src)[3];
        *(float4*)&hs[ldst + 0] = v0;
        *(float4*)&hs[ldst + 4] = v1;
        *(float4*)&hs[ldst + 8] = v2;
        *(float4*)&hs[ldst + 12] = v3;
      }
      __syncthreads();
      for (int s = 0; s < 32; ++s) {
        v2f a0 = (v2f){0.f, 0.f}, a1 = a0, a2 = a0, a3 = a0,
            a4 = a0, a5 = a0, a6 = a0, a7 = a0;
        const float4* h4 = (const float4*)&hs[s * 8 * HSL + rbase];
        #pragma unroll
        for (int qq = 0; qq < 4; ++qq) {
          float4 hv = h4[qq];
          v2f hA = (v2f){hv.x, hv.y}, hB = (v2f){hv.z, hv.w};
          a0 = pk_fma(hA, w2[2*qq][0], a0);
          a1 = pk_fma(hA, w2[2*qq][1], a1);
          a2 = pk_fma(hA, w2[2*qq][2], a2);
          a3 = pk_fma(hA, w2[2*qq][3], a3);
          a4 = pk_fma(hA, w2[2*qq][4], a4);
          a5 = pk_fma(hA, w2[2*qq][5], a5);
          a6 = pk_fma(hA, w2[2*qq][6], a6);
          a7 = pk_fma(hA, w2[2*qq][7], a7);
          a0 = pk_fma(hB, w2[2*qq+1][0], a0);
          a1 = pk_fma(hB, w2[2*qq+1][1], a1);
          a2 = pk_fma(hB, w2[2*qq+1][2], a2);
          a3 = pk_fma(hB, w2[2*qq+1][3], a3);
          a4 = pk_fma(hB, w2[2*qq+1][4], a4);
          a5 = pk_fma(hB, w2[2*qq+1][5], a5);
          a6 = pk_fma(hB, w2[2*qq+1][6], a6);
          a7 = pk_fma(hB, w2[2*qq+1][7], a7);
        }
        float s0 = row16_sum(a0.x + a0.y), s1 = row16_sum(a1.x + a1.y);
        float s2 = row16_sum(a2.x + a2.y), s3 = row16_sum(a3.x + a3.y);
        float s4 = row16_sum(a4.x + a4.y), s5 = row16_sum(a5.x + a5.y);
        float s6 = row16_sum(a6.x + a6.y), s7 = row16_sum(a7.x + a7.y);
        ureg[s & 7] = sel8(ks, s0, s1, s2, s3, s4, s5, s6, s7) + b2j;
        if ((s & 7) == 7 && writer) {
          float* dst = ub + (size_t)(blk * 32 + s - 7) * Hn + jcol;
          #pragma unroll
          for (int i = 0; i < 8; ++i) dst[i * Hn] = ureg[i];
        }
      }
      __syncthreads();
    }
  }
}

// ---------------------------------------------------------------------------
// Scan 2: h2_t = tanh(u2_t + h2_{t-1}@Wh2). R6 structure + pk_fma asm.
// ---------------------------------------------------------------------------
__global__ __launch_bounds__(512, 2) void scan2_kernel(
    const float* __restrict__ U,    // [B,T,256] = h1@Wx2 + b2
    const float* __restrict__ Wh2,  // [256,256]
    float* __restrict__ hfinal) {   // [B,256]
  __shared__ alignas(16) float hc[2][8 * HSL];
  const int tid = threadIdx.x;
  const int ks = tid & 15;
  const int cg = tid >> 4;
  const int col0 = 8 * cg;
  const int b = blockIdx.x;
  const float* Ub = U + (size_t)b * Tn * Hn;

  v2f wh[8][8];
  #pragma unroll
  for (int p = 0; p < 8; ++p) {
    const float* r0 = Wh2 + (size_t)(16 * ks + 2 * p) * Hn + col0;
    float4 a0 = *(const float4*)r0, a1 = *(const float4*)(r0 + 4);
    float4 c0 = *(const float4*)(r0 + Hn), c1 = *(const float4*)(r0 + Hn + 4);
    wh[p][0] = (v2f){a0.x, c0.x}; wh[p][1] = (v2f){a0.y, c0.y};
    wh[p][2] = (v2f){a0.z, c0.z}; wh[p][3] = (v2f){a0.w, c0.w};
    wh[p][4] = (v2f){a1.x, c1.x}; wh[p][5] = (v2f){a1.y, c1.y};
    wh[p][6] = (v2f){a1.z, c1.z}; wh[p][7] = (v2f){a1.w, c1.w};
  }
  const int jcol = col0 + (ks & 7);
  const bool writer = (ks < 8);
  const int sidx = (jcol >> 5) * HSL + (jcol & 31);
  const int rbase = (ks >> 1) * HSL + ((ks & 1) << 4);

  for (int i = tid; i < 2 * 8 * HSL; i += 512) (&hc[0][0])[i] = 0.f;
  __syncthreads();

  float ucur[8], unxt[8];
  if (writer) {
    #pragma unroll
    for (int i = 0; i < 8; ++i) ucur[i] = Ub[(size_t)i * Hn + jcol];
  }

  for (int t8 = 0; t8 < 128; ++t8) {
    #pragma unroll
    for (int s = 0; s < 8; ++s) {
      const int cu = s & 1, nx = cu ^ 1;
      if (s == 0 && writer && t8 < 127) {
        #pragma unroll
        for (int i = 0; i < 8; ++i)
          unxt[i] = Ub[(size_t)(t8 * 8 + 8 + i) * Hn + jcol];
      }
      v2f a0 = (v2f){0.f, 0.f}, a1 = a0, a2 = a0, a3 = a0,
          a4 = a0, a5 = a0, a6 = a0, a7 = a0;
      const float4* h4 = (const float4*)&hc[cu][rbase];
      #pragma unroll
      for (int qq = 0; qq < 4; ++qq) {
        float4 hv = h4[qq];
        v2f hA = (v2f){hv.x, hv.y}, hB = (v2f){hv.z, hv.w};
        a0 = pk_fma(hA, wh[2*qq][0], a0);
        a1 = pk_fma(hA, wh[2*qq][1], a1);
        a2 = pk_fma(hA, wh[2*qq][2], a2);
        a3 = pk_fma(hA, wh[2*qq][3], a3);
        a4 = pk_fma(hA, wh[2*qq][4], a4);
        a5 = pk_fma(hA, wh[2*qq][5], a5);
        a6 = pk_fma(hA, wh[2*qq][6], a6);
        a7 = pk_fma(hA, wh[2*qq][7], a7);
        a0 = pk_fma(hB, wh[2*qq+1][0], a0);
        a1 = pk_fma(hB, wh[2*qq+1][1], a1);
        a2 = pk_fma(hB, wh[2*qq+1][2], a2);
        a3 = pk_fma(hB, wh[2*qq+1][3], a3);
        a4 = pk_fma(hB, wh[2*qq+1][4], a4);
        a5 = pk_fma(hB, wh[2*qq+1][5], a5);
        a6 = pk_fma(hB, wh[2*qq+1][6], a6);
        a7 = pk_fma(hB, wh[2*qq+1][7], a7);
      }
      float s0 = row16_sum(a0.x + a0.y), s1 = row16_sum(a1.x + a1.y);
      float s2 = row16_sum(a2.x + a2.y), s3 = row16_sum(a3.x + a3.y);
      float s4 = row16_sum(a4.x + a4.y), s5 = row16_sum(a5.x + a5.y);
      float s6 = row16_sum(a6.x + a6.y), s7 = row16_sum(a7.x + a7.y);
      float h = fast_tanh(sel8(ks, s0, s1, s2, s3, s4, s5, s6, s7) + ucur[s]);
      if (writer) hc[nx][sidx] = h;
      if (s == 7) {
        #pragma unroll
        for (int i = 0; i < 8; ++i) ucur[i] = unxt[i];
      }
      __syncthreads();
    }
  }
  if (tid < Hn)
    hfinal[(size_t)b * Hn + tid] = hc[0][(tid >> 5) * HSL + (tid & 31)];
}

// ---------------------------------------------------------------------------
// Head: out = softmax(h2_T @ Wd + bd). Unchanged.
// ---------------------------------------------------------------------------
__global__ __launch_bounds__(128) void head_kernel(
    const float* __restrict__ hfinal, const float* __restrict__ Wd,
    const float* __restrict__ bd, float* __restrict__ out) {
  __shared__ float hrow[Hn];
  __shared__ float red[On];
  const int o = threadIdx.x;
  const int b = blockIdx.x;
  hrow[o] = hfinal[(size_t)b * Hn + o];
  hrow[o + 128] = hfinal[(size_t)b * Hn + 128 + o];
  __syncthreads();
  float acc = bd[o];
  #pragma unroll 8
  for (int k = 0; k < Hn; ++k) acc = fmaf(hrow[k], Wd[(size_t)k * On + o], acc);
  red[o] = acc;
  __syncthreads();
  #pragma unroll
  for (int s = 64; s > 0; s >>= 1) {
    if (o < s) red[o] = fmaxf(red[o], red[o + s]);
    __syncthreads();
  }
  const float mx = red[0];
  __syncthreads();
  const float e = __expf(acc - mx);
  red[o] = e;
  __syncthreads();
  #pragma unroll
  for (int s = 64; s > 0; s >>= 1) {
    if (o < s) red[o] += red[o + s];
    __syncthreads();
  }
  out[(size_t)b * On + o] = e / red[0];
}

// ---------------------------------------------------------------------------
extern "C" void kernel_launch(void* const* d_in, const int* in_sizes, int n_in,
                              void* d_out, int out_size, void* d_ws, size_t ws_size,
                              hipStream_t stream) {
  const float* x   = (const float*)d_in[0];
  const float* Wx1 = (const float*)d_in[1];
  const float* Wh1 = (const float*)d_in[2];
  const float* b1  = (const float*)d_in[3];
  const float* Wx2 = (const float*)d_in[4];
  const float* Wh2 = (const float*)d_in[5];
  const float* b2  = (const float*)d_in[6];
  const float* Wd  = (const float*)d_in[7];
  const float* bd  = (const float*)d_in[8];
  float* out = (float*)d_out;

  float* buf = (float*)d_ws;                      // h1 -> (in-place) u2
  float* hfinal = buf + (size_t)Bn * Tn * Hn;     // [B*256]
  int* flags = (int*)(hfinal + (size_t)Bn * Hn);  // [B]

  hipMemsetAsync(flags, 0, Bn * sizeof(int), stream);
  stage1_kernel<<<2 * Bn, 512, 0, stream>>>(x, Wx1, Wh1, b1, Wx2, b2, buf, flags);
  scan2_kernel<<<Bn, 512, 0, stream>>>(buf, Wh2, hfinal);
  head_kernel<<<Bn, 128, 0, stream>>>(hfinal, Wd, bd, out);
}

// Round 11
// 1487.041 us; speedup vs baseline: 1.0510x; 1.0281x over previous
//
#include <hip/hip_runtime.h>
#include <cstdint>

constexpr int Bn = 128, Tn = 1024, Dn = 64, Hn = 256, On = 128;
constexpr int HSL = 36;  // padded LDS slice stride (32 data + 4 pad)

typedef float v2f __attribute__((ext_vector_type(2)));

__device__ __forceinline__ float fast_tanh(float x) {
  float e = __expf(2.0f * x);
  return 1.0f - 2.0f / (e + 1.0f);
}

// Force a value to live in a VGPR: the asm makes it opaque, so the compiler
// cannot rematerialize the originating global load inside the scan loop.
// R1..R10 all had VGPR_Count < declared weight count (108 vs 160) -> weights
// were re-loaded from L1/L2 every step (~327 KB/WG/step). This pins them.
__device__ __forceinline__ void pin(v2f& w) { asm volatile("" : "+v"(w)); }

template <int CTRL>
__device__ __forceinline__ float dpp_add(float v) {
  int s = __builtin_amdgcn_update_dpp(0, __float_as_int(v), CTRL, 0xF, 0xF, true);
  return v + __int_as_float(s);
}
__device__ __forceinline__ float row16_sum(float v) {
  v = dpp_add<0xB1>(v);   // quad_perm xor1
  v = dpp_add<0x4E>(v);   // quad_perm xor2
  v = dpp_add<0x141>(v);  // ROW_HALF_MIRROR == xor4
  v = dpp_add<0x140>(v);  // ROW_MIRROR == xor8
  return v;
}

__device__ __forceinline__ float sel8(int ks, float s0, float s1, float s2,
                                      float s3, float s4, float s5, float s6,
                                      float s7) {
  float u0 = (ks & 1) ? s1 : s0;
  float u1 = (ks & 1) ? s3 : s2;
  float u2 = (ks & 1) ? s5 : s4;
  float u3 = (ks & 1) ? s7 : s6;
  float v0 = (ks & 2) ? u1 : u0;
  float v1 = (ks & 2) ? u3 : u2;
  return (ks & 4) ? v1 : v0;
}

// ---------------------------------------------------------------------------
// Stage 1 (256 WGs) — R7 structure (best measured: 1473 us total):
//   WGs [0,128):   role A — scan1 producer, releases flags[b]/32-step block
//   WGs [128,256): role B — u2 = h1@Wx2+b2 in place, cheap, tracks A
// ---------------------------------------------------------------------------
__global__ __launch_bounds__(512, 2) void stage1_kernel(
    const float* __restrict__ x,    // [B,T,64]
    const float* __restrict__ Wx1,  // [64,256]
    const float* __restrict__ Wh1,  // [256,256]
    const float* __restrict__ b1,   // [256]
    const float* __restrict__ Wx2,  // [256,256]
    const float* __restrict__ b2,   // [256]
    float* __restrict__ h1buf,      // [B,T,256] h1 then (in-place) u2
    int* __restrict__ flags) {      // [B]
  __shared__ alignas(16) float smem[32 * 8 * HSL];
  const int tid = threadIdx.x;
  const int ks = tid & 15;
  const int cg = tid >> 4;
  const int col0 = 8 * cg;
  const int jcol = col0 + (ks & 7);
  const bool writer = (ks < 8);

  if (blockIdx.x < Bn) {
    // ================= ROLE A: scan1 producer =================
    const int b = blockIdx.x;
    const float* xb = x + (size_t)b * Tn * Dn;
    float* hb = h1buf + (size_t)b * Tn * Hn;
    float* hc0 = smem;          // [2][8*HSL]
    float* xs0 = smem + 576;    // [2][2048]

    v2f wh[8][8];
    #pragma unroll
    for (int p = 0; p < 8; ++p) {
      const float* r0 = Wh1 + (size_t)(16 * ks + 2 * p) * Hn + col0;
      float4 a0 = *(const float4*)r0, a1 = *(const float4*)(r0 + 4);
      float4 c0 = *(const float4*)(r0 + Hn), c1 = *(const float4*)(r0 + Hn + 4);
      wh[p][0] = (v2f){a0.x, c0.x}; wh[p][1] = (v2f){a0.y, c0.y};
      wh[p][2] = (v2f){a0.z, c0.z}; wh[p][3] = (v2f){a0.w, c0.w};
      wh[p][4] = (v2f){a1.x, c1.x}; wh[p][5] = (v2f){a1.y, c1.y};
      wh[p][6] = (v2f){a1.z, c1.z}; wh[p][7] = (v2f){a1.w, c1.w};
    }
    v2f wx[2][8];
    #pragma unroll
    for (int p = 0; p < 2; ++p) {
      const float* r0 = Wx1 + (size_t)(4 * ks + 2 * p) * Hn + col0;
      float4 a0 = *(const float4*)r0, a1 = *(const float4*)(r0 + 4);
      float4 c0 = *(const float4*)(r0 + Hn), c1 = *(const float4*)(r0 + Hn + 4);
      wx[p][0] = (v2f){a0.x, c0.x}; wx[p][1] = (v2f){a0.y, c0.y};
      wx[p][2] = (v2f){a0.z, c0.z}; wx[p][3] = (v2f){a0.w, c0.w};
      wx[p][4] = (v2f){a1.x, c1.x}; wx[p][5] = (v2f){a1.y, c1.y};
      wx[p][6] = (v2f){a1.z, c1.z}; wx[p][7] = (v2f){a1.w, c1.w};
    }
    #pragma unroll
    for (int p = 0; p < 8; ++p)
      #pragma unroll
      for (int c = 0; c < 8; ++c) pin(wh[p][c]);
    #pragma unroll
    for (int p = 0; p < 2; ++p)
      #pragma unroll
      for (int c = 0; c < 8; ++c) pin(wx[p][c]);

    const float bj = b1[jcol];
    const int sidx = (jcol >> 5) * HSL + (jcol & 31);
    const int rbase = (ks >> 1) * HSL + ((ks & 1) << 4);

    for (int i = tid; i < 2 * 8 * HSL; i += 512) hc0[i] = 0.f;
    *(float4*)&xs0[4 * tid] = *(const float4*)(xb + 4 * tid);
    __syncthreads();

    float hreg[8];
    float4 xr = make_float4(0.f, 0.f, 0.f, 0.f);
    for (int t8 = 0; t8 < 128; ++t8) {
      const int xcur = (t8 >> 2) & 1;
      #pragma unroll
      for (int s = 0; s < 8; ++s) {
        const int t = t8 * 8 + s;
        const int cu = s & 1, nx = cu ^ 1;
        if (s == 0 && (t8 & 3) == 0 && t8 < 124)
          xr = *(const float4*)(xb + (size_t)((t8 >> 2) + 1) * 2048 + 4 * tid);

        v2f a0 = (v2f){0.f, 0.f}, a1 = a0, a2 = a0, a3 = a0,
            a4 = a0, a5 = a0, a6 = a0, a7 = a0;
        const float4* h4 = (const float4*)&hc0[cu * 8 * HSL + rbase];
        #pragma unroll
        for (int qq = 0; qq < 4; ++qq) {
          float4 hv = h4[qq];
          v2f hA = (v2f){hv.x, hv.y}, hB = (v2f){hv.z, hv.w};
          a0 = __builtin_elementwise_fma(hA, wh[2*qq][0], a0);
          a1 = __builtin_elementwise_fma(hA, wh[2*qq][1], a1);
          a2 = __builtin_elementwise_fma(hA, wh[2*qq][2], a2);
          a3 = __builtin_elementwise_fma(hA, wh[2*qq][3], a3);
          a4 = __builtin_elementwise_fma(hA, wh[2*qq][4], a4);
          a5 = __builtin_elementwise_fma(hA, wh[2*qq][5], a5);
          a6 = __builtin_elementwise_fma(hA, wh[2*qq][6], a6);
          a7 = __builtin_elementwise_fma(hA, wh[2*qq][7], a7);
          a0 = __builtin_elementwise_fma(hB, wh[2*qq+1][0], a0);
          a1 = __builtin_elementwise_fma(hB, wh[2*qq+1][1], a1);
          a2 = __builtin_elementwise_fma(hB, wh[2*qq+1][2], a2);
          a3 = __builtin_elementwise_fma(hB, wh[2*qq+1][3], a3);
          a4 = __builtin_elementwise_fma(hB, wh[2*qq+1][4], a4);
          a5 = __builtin_elementwise_fma(hB, wh[2*qq+1][5], a5);
          a6 = __builtin_elementwise_fma(hB, wh[2*qq+1][6], a6);
          a7 = __builtin_elementwise_fma(hB, wh[2*qq+1][7], a7);
        }
        {
          float4 xv = *(const float4*)&xs0[xcur * 2048 + ((t & 31) << 6) + 4 * ks];
          v2f xA = (v2f){xv.x, xv.y}, xB = (v2f){xv.z, xv.w};
          a0 = __builtin_elementwise_fma(xA, wx[0][0], a0);
          a1 = __builtin_elementwise_fma(xA, wx[0][1], a1);
          a2 = __builtin_elementwise_fma(xA, wx[0][2], a2);
          a3 = __builtin_elementwise_fma(xA, wx[0][3], a3);
          a4 = __builtin_elementwise_fma(xA, wx[0][4], a4);
          a5 = __builtin_elementwise_fma(xA, wx[0][5], a5);
          a6 = __builtin_elementwise_fma(xA, wx[0][6], a6);
          a7 = __builtin_elementwise_fma(xA, wx[0][7], a7);
          a0 = __builtin_elementwise_fma(xB, wx[1][0], a0);
          a1 = __builtin_elementwise_fma(xB, wx[1][1], a1);
          a2 = __builtin_elementwise_fma(xB, wx[1][2], a2);
          a3 = __builtin_elementwise_fma(xB, wx[1][3], a3);
          a4 = __builtin_elementwise_fma(xB, wx[1][4], a4);
          a5 = __builtin_elementwise_fma(xB, wx[1][5], a5);
          a6 = __builtin_elementwise_fma(xB, wx[1][6], a6);
          a7 = __builtin_elementwise_fma(xB, wx[1][7], a7);
        }
        float s0 = row16_sum(a0.x + a0.y), s1 = row16_sum(a1.x + a1.y);
        float s2 = row16_sum(a2.x + a2.y), s3 = row16_sum(a3.x + a3.y);
        float s4 = row16_sum(a4.x + a4.y), s5 = row16_sum(a5.x + a5.y);
        float s6 = row16_sum(a6.x + a6.y), s7 = row16_sum(a7.x + a7.y);
        float h = fast_tanh(sel8(ks, s0, s1, s2, s3, s4, s5, s6, s7) + bj);
        if (writer) hc0[nx * 8 * HSL + sidx] = h;
        hreg[s] = h;
        if (s == 7) {
          if (writer) {
            float* dst = hb + (size_t)(t - 7) * Hn + jcol;
            #pragma unroll
            for (int i = 0; i < 8; ++i) dst[i * Hn] = hreg[i];
          }
          if ((t8 & 3) == 3 && t8 < 127) *(float4*)&xs0[(xcur ^ 1) * 2048 + 4 * tid] = xr;
        }
        __syncthreads();  // vmcnt(0) drained -> safe to release
        if (s == 7 && (t8 & 3) == 3 && tid == 0)
          __hip_atomic_store(flags + b, (t8 >> 2) + 1, __ATOMIC_RELEASE,
                             __HIP_MEMORY_SCOPE_AGENT);
      }
    }
  } else {
    // ================= ROLE B: u2 consumer =================
    const int b = blockIdx.x - Bn;
    float* ub = h1buf + (size_t)b * Tn * Hn;  // read h1, overwrite with u2
    float* hs = smem;                          // [32][8*HSL]

    v2f w2[8][8];
    #pragma unroll
    for (int p = 0; p < 8; ++p) {
      const float* r0 = Wx2 + (size_t)(16 * ks + 2 * p) * Hn + col0;
      float4 a0 = *(const float4*)r0, a1 = *(const float4*)(r0 + 4);
      float4 c0 = *(const float4*)(r0 + Hn), c1 = *(const float4*)(r0 + Hn + 4);
      w2[p][0] = (v2f){a0.x, c0.x}; w2[p][1] = (v2f){a0.y, c0.y};
      w2[p][2] = (v2f){a0.z, c0.z}; w2[p][3] = (v2f){a0.w, c0.w};
      w2[p][4] = (v2f){a1.x, c1.x}; w2[p][5] = (v2f){a1.y, c1.y};
      w2[p][6] = (v2f){a1.z, c1.z}; w2[p][7] = (v2f){a1.w, c1.w};
    }
    #pragma unroll
    for (int p = 0; p < 8; ++p)
      #pragma unroll
      for (int c = 0; c < 8; ++c) pin(w2[p][c]);

    const float b2j = b2[jcol];
    const int rbase = (ks >> 1) * HSL + ((ks & 1) << 4);
    const int lr = tid >> 4;
    const int lcb = (tid & 15) * 16;
    const int ldst = lr * 8 * HSL + (lcb >> 5) * HSL + (lcb & 31);

    float ureg[8];
    for (int blk = 0; blk < 32; ++blk) {
      if (tid == 0) {
        while (__hip_atomic_load(flags + b, __ATOMIC_ACQUIRE,
                                 __HIP_MEMORY_SCOPE_AGENT) < blk + 1)
          __builtin_amdgcn_s_sleep(8);
      }
      __syncthreads();
      {
        const float* src = ub + (size_t)(blk * 32 + lr) * Hn + lcb;
        float4 v0 = ((const float4*)src)[0];
        float4 v1 = ((const float4*)src)[1];
        float4 v2 = ((const float4*)src)[2];
        float4 v3 = ((const float4*)src)[3];
        *(float4*)&hs[ldst + 0] = v0;
        *(float4*)&hs[ldst + 4] = v1;
        *(float4*)&hs[ldst + 8] = v2;
        *(float4*)&hs[ldst + 12] = v3;
      }
      __syncthreads();
      for (int s = 0; s < 32; ++s) {
        v2f a0 = (v2f){0.f, 0.f}, a1 = a0, a2 = a0, a3 = a0,
            a4 = a0, a5 = a0, a6 = a0, a7 = a0;
        const float4* h4 = (const float4*)&hs[s * 8 * HSL + rbase];
        #pragma unroll
        for (int qq = 0; qq < 4; ++qq) {
          float4 hv = h4[qq];
          v2f hA = (v2f){hv.x, hv.y}, hB = (v2f){hv.z, hv.w};
          a0 = __builtin_elementwise_fma(hA, w2[2*qq][0], a0);
          a1 = __builtin_elementwise_fma(hA, w2[2*qq][1], a1);
          a2 = __builtin_elementwise_fma(hA, w2[2*qq][2], a2);
          a3 = __builtin_elementwise_fma(hA, w2[2*qq][3], a3);
          a4 = __builtin_elementwise_fma(hA, w2[2*qq][4], a4);
          a5 = __builtin_elementwise_fma(hA, w2[2*qq][5], a5);
          a6 = __builtin_elementwise_fma(hA, w2[2*qq][6], a6);
          a7 = __builtin_elementwise_fma(hA, w2[2*qq][7], a7);
          a0 = __builtin_elementwise_fma(hB, w2[2*qq+1][0], a0);
          a1 = __builtin_elementwise_fma(hB, w2[2*qq+1][1], a1);
          a2 = __builtin_elementwise_fma(hB, w2[2*qq+1][2], a2);
          a3 = __builtin_elementwise_fma(hB, w2[2*qq+1][3], a3);
          a4 = __builtin_elementwise_fma(hB, w2[2*qq+1][4], a4);
          a5 = __builtin_elementwise_fma(hB, w2[2*qq+1][5], a5);
          a6 = __builtin_elementwise_fma(hB, w2[2*qq+1][6], a6);
          a7 = __builtin_elementwise_fma(hB, w2[2*qq+1][7], a7);
        }
        float s0 = row16_sum(a0.x + a0.y), s1 = row16_sum(a1.x + a1.y);
        float s2 = row16_sum(a2.x + a2.y), s3 = row16_sum(a3.x + a3.y);
        float s4 = row16_sum(a4.x + a4.y), s5 = row16_sum(a5.x + a5.y);
        float s6 = row16_sum(a6.x + a6.y), s7 = row16_sum(a7.x + a7.y);
        ureg[s & 7] = sel8(ks, s0, s1, s2, s3, s4, s5, s6, s7) + b2j;
        if ((s & 7) == 7 && writer) {
          float* dst = ub + (size_t)(blk * 32 + s - 7) * Hn + jcol;
          #pragma unroll
          for (int i = 0; i < 8; ++i) dst[i * Hn] = ureg[i];
        }
      }
      __syncthreads();
    }
  }
}

// ---------------------------------------------------------------------------
// Scan 2: h2_t = tanh(u2_t + h2_{t-1}@Wh2). R6 structure + weight pinning.
// ---------------------------------------------------------------------------
__global__ __launch_bounds__(512, 2) void scan2_kernel(
    const float* __restrict__ U,    // [B,T,256] = h1@Wx2 + b2
    const float* __restrict__ Wh2,  // [256,256]
    float* __restrict__ hfinal) {   // [B,256]
  __shared__ alignas(16) float hc[2][8 * HSL];
  const int tid = threadIdx.x;
  const int ks = tid & 15;
  const int cg = tid >> 4;
  const int col0 = 8 * cg;
  const int b = blockIdx.x;
  const float* Ub = U + (size_t)b * Tn * Hn;

  v2f wh[8][8];
  #pragma unroll
  for (int p = 0; p < 8; ++p) {
    const float* r0 = Wh2 + (size_t)(16 * ks + 2 * p) * Hn + col0;
    float4 a0 = *(const float4*)r0, a1 = *(const float4*)(r0 + 4);
    float4 c0 = *(const float4*)(r0 + Hn), c1 = *(const float4*)(r0 + Hn + 4);
    wh[p][0] = (v2f){a0.x, c0.x}; wh[p][1] = (v2f){a0.y, c0.y};
    wh[p][2] = (v2f){a0.z, c0.z}; wh[p][3] = (v2f){a0.w, c0.w};
    wh[p][4] = (v2f){a1.x, c1.x}; wh[p][5] = (v2f){a1.y, c1.y};
    wh[p][6] = (v2f){a1.z, c1.z}; wh[p][7] = (v2f){a1.w, c1.w};
  }
  #pragma unroll
  for (int p = 0; p < 8; ++p)
    #pragma unroll
    for (int c = 0; c < 8; ++c) pin(wh[p][c]);

  const int jcol = col0 + (ks & 7);
  const bool writer = (ks < 8);
  const int sidx = (jcol >> 5) * HSL + (jcol & 31);
  const int rbase = (ks >> 1) * HSL + ((ks & 1) << 4);

  for (int i = tid; i < 2 * 8 * HSL; i += 512) (&hc[0][0])[i] = 0.f;
  __syncthreads();

  float ucur[8], unxt[8];
  if (writer) {
    #pragma unroll
    for (int i = 0; i < 8; ++i) ucur[i] = Ub[(size_t)i * Hn + jcol];
  }

  for (int t8 = 0; t8 < 128; ++t8) {
    #pragma unroll
    for (int s = 0; s < 8; ++s) {
      const int cu = s & 1, nx = cu ^ 1;
      if (s == 0 && writer && t8 < 127) {
        #pragma unroll
        for (int i = 0; i < 8; ++i)
          unxt[i] = Ub[(size_t)(t8 * 8 + 8 + i) * Hn + jcol];
      }
      v2f a0 = (v2f){0.f, 0.f}, a1 = a0, a2 = a0, a3 = a0,
          a4 = a0, a5 = a0, a6 = a0, a7 = a0;
      const float4* h4 = (const float4*)&hc[cu][rbase];
      #pragma unroll
      for (int qq = 0; qq < 4; ++qq) {
        float4 hv = h4[qq];
        v2f hA = (v2f){hv.x, hv.y}, hB = (v2f){hv.z, hv.w};
        a0 = __builtin_elementwise_fma(hA, wh[2*qq][0], a0);
        a1 = __builtin_elementwise_fma(hA, wh[2*qq][1], a1);
        a2 = __builtin_elementwise_fma(hA, wh[2*qq][2], a2);
        a3 = __builtin_elementwise_fma(hA, wh[2*qq][3], a3);
        a4 = __builtin_elementwise_fma(hA, wh[2*qq][4], a4);
        a5 = __builtin_elementwise_fma(hA, wh[2*qq][5], a5);
        a6 = __builtin_elementwise_fma(hA, wh[2*qq][6], a6);
        a7 = __builtin_elementwise_fma(hA, wh[2*qq][7], a7);
        a0 = __builtin_elementwise_fma(hB, wh[2*qq+1][0], a0);
        a1 = __builtin_elementwise_fma(hB, wh[2*qq+1][1], a1);
        a2 = __builtin_elementwise_fma(hB, wh[2*qq+1][2], a2);
        a3 = __builtin_elementwise_fma(hB, wh[2*qq+1][3], a3);
        a4 = __builtin_elementwise_fma(hB, wh[2*qq+1][4], a4);
        a5 = __builtin_elementwise_fma(hB, wh[2*qq+1][5], a5);
        a6 = __builtin_elementwise_fma(hB, wh[2*qq+1][6], a6);
        a7 = __builtin_elementwise_fma(hB, wh[2*qq+1][7], a7);
      }
      float s0 = row16_sum(a0.x + a0.y), s1 = row16_sum(a1.x + a1.y);
      float s2 = row16_sum(a2.x + a2.y), s3 = row16_sum(a3.x + a3.y);
      float s4 = row16_sum(a4.x + a4.y), s5 = row16_sum(a5.x + a5.y);
      float s6 = row16_sum(a6.x + a6.y), s7 = row16_sum(a7.x + a7.y);
      float h = fast_tanh(sel8(ks, s0, s1, s2, s3, s4, s5, s6, s7) + ucur[s]);
      if (writer) hc[nx][sidx] = h;
      if (s == 7) {
        #pragma unroll
        for (int i = 0; i < 8; ++i) ucur[i] = unxt[i];
      }
      __syncthreads();
    }
  }
  if (tid < Hn)
    hfinal[(size_t)b * Hn + tid] = hc[0][(tid >> 5) * HSL + (tid & 31)];
}

// ---------------------------------------------------------------------------
// Head: out = softmax(h2_T @ Wd + bd). Unchanged.
// ---------------------------------------------------------------------------
__global__ __launch_bounds__(128) void head_kernel(
    const float* __restrict__ hfinal, const float* __restrict__ Wd,
    const float* __restrict__ bd, float* __restrict__ out) {
  __shared__ float hrow[Hn];
  __shared__ float red[On];
  const int o = threadIdx.x;
  const int b = blockIdx.x;
  hrow[o] = hfinal[(size_t)b * Hn + o];
  hrow[o + 128] = hfinal[(size_t)b * Hn + 128 + o];
  __syncthreads();
  float acc = bd[o];
  #pragma unroll 8
  for (int k = 0; k < Hn; ++k) acc = fmaf(hrow[k], Wd[(size_t)k * On + o], acc);
  red[o] = acc;
  __syncthreads();
  #pragma unroll
  for (int s = 64; s > 0; s >>= 1) {
    if (o < s) red[o] = fmaxf(red[o], red[o + s]);
    __syncthreads();
  }
  const float mx = red[0];
  __syncthreads();
  const float e = __expf(acc - mx);
  red[o] = e;
  __syncthreads();
  #pragma unroll
  for (int s = 64; s > 0; s >>= 1) {
    if (o < s) red[o] += red[o + s];
    __syncthreads();
  }
  out[(size_t)b * On + o] = e / red[0];
}

// ---------------------------------------------------------------------------
extern "C" void kernel_launch(void* const* d_in, const int* in_sizes, int n_in,
                              void* d_out, int out_size, void* d_ws, size_t ws_size,
                              hipStream_t stream) {
  const float* x   = (const float*)d_in[0];
  const float* Wx1 = (const float*)d_in[1];
  const float* Wh1 = (const float*)d_in[2];
  const float* b1  = (const float*)d_in[3];
  const float* Wx2 = (const float*)d_in[4];
  const float* Wh2 = (const float*)d_in[5];
  const float* b2  = (const float*)d_in[6];
  const float* Wd  = (const float*)d_in[7];
  const float* bd  = (const float*)d_in[8];
  float* out = (float*)d_out;

  float* buf = (float*)d_ws;                      // h1 -> (in-place) u2
  float* hfinal = buf + (size_t)Bn * Tn * Hn;     // [B*256]
  int* flags = (int*)(hfinal + (size_t)Bn * Hn);  // [B]

  hipMemsetAsync(flags, 0, Bn * sizeof(int), stream);
  stage1_kernel<<<2 * Bn, 512, 0, stream>>>(x, Wx1, Wh1, b1, Wx2, b2, buf, flags);
  scan2_kernel<<<Bn, 512, 0, stream>>>(buf, Wh2, hfinal);
  head_kernel<<<Bn, 128, 0, stream>>>(hfinal, Wd, bd, out);
}

// Round 12
// 1431.760 us; speedup vs baseline: 1.0916x; 1.0386x over previous
//
#include <hip/hip_runtime.h>
#include <cstdint>

constexpr int Bn = 128, Tn = 1024, Dn = 64, Hn = 256, On = 128;

typedef __fp16 h2 __attribute__((ext_vector_type(2)));
typedef unsigned short u16;

__device__ __forceinline__ float fast_tanh(float x) {
  float e = __expf(2.0f * x);
  return 1.0f - 2.0f / (e + 1.0f);
}

// v_dot2_f32_f16: 2 f16 MACs with f32 accumulate, full VALU rate.
__device__ __forceinline__ float fdot2(h2 a, h2 b, float c) {
#if __has_builtin(__builtin_amdgcn_fdot2)
  return __builtin_amdgcn_fdot2(a, b, c, false);
#else
  return fmaf((float)a.y, (float)b.y, fmaf((float)a.x, (float)b.x, c));
#endif
}

__device__ __forceinline__ h2 pk2(float a, float b) {
  h2 r; r.x = (__fp16)a; r.y = (__fp16)b; return r;
}
__device__ __forceinline__ h2 bits2h(unsigned u) { return __builtin_bit_cast(h2, u); }
__device__ __forceinline__ unsigned h2bits(h2 v) { return __builtin_bit_cast(unsigned, v); }
__device__ __forceinline__ u16 f2hb(float f) {
  __fp16 h = (__fp16)f; return __builtin_bit_cast(u16, h);
}
__device__ __forceinline__ float hb2f(u16 b) {
  return (float)__builtin_bit_cast(__fp16, b);
}
__device__ __forceinline__ void pin16(h2& w) { asm volatile("" : "+v"(w)); }

template <int CTRL>
__device__ __forceinline__ float dpp_add(float v) {
  int s = __builtin_amdgcn_update_dpp(0, __float_as_int(v), CTRL, 0xF, 0xF, true);
  return v + __int_as_float(s);
}
__device__ __forceinline__ float row16_sum(float v) {
  v = dpp_add<0xB1>(v);   // quad_perm xor1
  v = dpp_add<0x4E>(v);   // quad_perm xor2
  v = dpp_add<0x141>(v);  // ROW_HALF_MIRROR == xor4
  v = dpp_add<0x140>(v);  // ROW_MIRROR == xor8
  return v;
}
__device__ __forceinline__ float sel8(int ks, float s0, float s1, float s2,
                                      float s3, float s4, float s5, float s6,
                                      float s7) {
  float u0 = (ks & 1) ? s1 : s0;
  float u1 = (ks & 1) ? s3 : s2;
  float u2 = (ks & 1) ? s5 : s4;
  float u3 = (ks & 1) ? s7 : s6;
  float v0 = (ks & 2) ? u1 : u0;
  float v1 = (ks & 2) ? u3 : u2;
  return (ks & 4) ? v1 : v0;
}

// LDS h layout (f16): 16 slices x (16 data + 4 pad) halfs; slice stride 40 B
// -> reader dwords 10*ks mod 32 all distinct, conflict-free; 8 B aligned.
// ---------------------------------------------------------------------------
// Stage 1 (256 WGs) — R7 pipeline: A = scan1 producer, B = u2 (in-place, f16).
// Weights f16 k-paired: 80 VGPRs/thread -> fits architectural (R1-R11: 160
// f32 weights were AGPR-spilled, +1 v_accvgpr_read per use = the VALU gap).
// ---------------------------------------------------------------------------
__global__ __launch_bounds__(512, 2) void stage1_kernel(
    const float* __restrict__ x,    // [B,T,64] f32
    const float* __restrict__ Wx1,  // [64,256] f32
    const float* __restrict__ Wh1,  // [256,256] f32
    const float* __restrict__ b1,   // [256]
    const float* __restrict__ Wx2,  // [256,256] f32
    const float* __restrict__ b2,   // [256]
    u16* __restrict__ h1b16,        // [B,T,256] f16: h1 then (in-place) u2
    int* __restrict__ flags) {      // [B]
  __shared__ alignas(16) u16 smemU[12288];  // 24 KB
  const int tid = threadIdx.x;
  const int ks = tid & 15;
  const int cg = tid >> 4;
  const int col0 = 8 * cg;
  const int jcol = col0 + (ks & 7);
  const bool writer = (ks < 8);

  if (blockIdx.x < Bn) {
    // ================= ROLE A: scan1 producer =================
    const int b = blockIdx.x;
    const float* xb = x + (size_t)b * Tn * Dn;
    u16* hb = h1b16 + (size_t)b * Tn * Hn;
    u16* hcH = smemU;          // 2 x 320 halfs
    u16* xsH = smemU + 768;    // 2 x 2048 halfs (32-step x blocks, f16)

    h2 wh[8][8];  // Wh1 k-pairs (16ks+2p, +1) x 8 cols
    #pragma unroll
    for (int p = 0; p < 8; ++p) {
      const float* r0 = Wh1 + (size_t)(16 * ks + 2 * p) * Hn + col0;
      float4 a0 = *(const float4*)r0, a1 = *(const float4*)(r0 + 4);
      float4 c0 = *(const float4*)(r0 + Hn), c1 = *(const float4*)(r0 + Hn + 4);
      wh[p][0] = pk2(a0.x, c0.x); wh[p][1] = pk2(a0.y, c0.y);
      wh[p][2] = pk2(a0.z, c0.z); wh[p][3] = pk2(a0.w, c0.w);
      wh[p][4] = pk2(a1.x, c1.x); wh[p][5] = pk2(a1.y, c1.y);
      wh[p][6] = pk2(a1.z, c1.z); wh[p][7] = pk2(a1.w, c1.w);
    }
    h2 wx[2][8];  // Wx1 k-pairs (4ks+2p, +1)
    #pragma unroll
    for (int p = 0; p < 2; ++p) {
      const float* r0 = Wx1 + (size_t)(4 * ks + 2 * p) * Hn + col0;
      float4 a0 = *(const float4*)r0, a1 = *(const float4*)(r0 + 4);
      float4 c0 = *(const float4*)(r0 + Hn), c1 = *(const float4*)(r0 + Hn + 4);
      wx[p][0] = pk2(a0.x, c0.x); wx[p][1] = pk2(a0.y, c0.y);
      wx[p][2] = pk2(a0.z, c0.z); wx[p][3] = pk2(a0.w, c0.w);
      wx[p][4] = pk2(a1.x, c1.x); wx[p][5] = pk2(a1.y, c1.y);
      wx[p][6] = pk2(a1.z, c1.z); wx[p][7] = pk2(a1.w, c1.w);
    }
    #pragma unroll
    for (int p = 0; p < 8; ++p)
      #pragma unroll
      for (int c = 0; c < 8; ++c) pin16(wh[p][c]);
    #pragma unroll
    for (int p = 0; p < 2; ++p)
      #pragma unroll
      for (int c = 0; c < 8; ++c) pin16(wx[p][c]);

    const float bj = b1[jcol];
    const int woffH = 20 * (jcol >> 4) + (jcol & 15);

    for (int i = tid; i < 640; i += 512) hcH[i] = 0;  // zero both h buffers
    {
      float4 x0 = *(const float4*)(xb + 4 * tid);  // block 0 -> f16 LDS
      ((uint2*)xsH)[tid] = make_uint2(h2bits(pk2(x0.x, x0.y)), h2bits(pk2(x0.z, x0.w)));
    }
    __syncthreads();

    u16 hreg[8];
    float4 xr = make_float4(0.f, 0.f, 0.f, 0.f);
    for (int t8 = 0; t8 < 128; ++t8) {
      const int xcur = (t8 >> 2) & 1;
      #pragma unroll
      for (int s = 0; s < 8; ++s) {
        const int t = t8 * 8 + s;
        const int cu = s & 1, nx = cu ^ 1;
        if (s == 0 && (t8 & 3) == 0 && t8 < 124)
          xr = *(const float4*)(xb + (size_t)((t8 >> 2) + 1) * 2048 + 4 * tid);

        const uint2* hq = (const uint2*)(hcH + cu * 320 + 20 * ks);
        uint2 q0 = hq[0], q1 = hq[1], q2 = hq[2], q3 = hq[3];
        uint2 xq = *(const uint2*)(xsH + xcur * 2048 + ((t & 31) << 6) + 4 * ks);
        float a0 = 0.f, a1 = 0.f, a2 = 0.f, a3 = 0.f,
              a4 = 0.f, a5 = 0.f, a6 = 0.f, a7 = 0.f;
        const unsigned d[8] = {q0.x, q0.y, q1.x, q1.y, q2.x, q2.y, q3.x, q3.y};
        #pragma unroll
        for (int p = 0; p < 8; ++p) {
          h2 hp = bits2h(d[p]);
          a0 = fdot2(hp, wh[p][0], a0);
          a1 = fdot2(hp, wh[p][1], a1);
          a2 = fdot2(hp, wh[p][2], a2);
          a3 = fdot2(hp, wh[p][3], a3);
          a4 = fdot2(hp, wh[p][4], a4);
          a5 = fdot2(hp, wh[p][5], a5);
          a6 = fdot2(hp, wh[p][6], a6);
          a7 = fdot2(hp, wh[p][7], a7);
        }
        {
          h2 xp0 = bits2h(xq.x), xp1 = bits2h(xq.y);
          a0 = fdot2(xp0, wx[0][0], a0); a0 = fdot2(xp1, wx[1][0], a0);
          a1 = fdot2(xp0, wx[0][1], a1); a1 = fdot2(xp1, wx[1][1], a1);
          a2 = fdot2(xp0, wx[0][2], a2); a2 = fdot2(xp1, wx[1][2], a2);
          a3 = fdot2(xp0, wx[0][3], a3); a3 = fdot2(xp1, wx[1][3], a3);
          a4 = fdot2(xp0, wx[0][4], a4); a4 = fdot2(xp1, wx[1][4], a4);
          a5 = fdot2(xp0, wx[0][5], a5); a5 = fdot2(xp1, wx[1][5], a5);
          a6 = fdot2(xp0, wx[0][6], a6); a6 = fdot2(xp1, wx[1][6], a6);
          a7 = fdot2(xp0, wx[0][7], a7); a7 = fdot2(xp1, wx[1][7], a7);
        }
        float s0 = row16_sum(a0), s1 = row16_sum(a1);
        float s2 = row16_sum(a2), s3 = row16_sum(a3);
        float s4 = row16_sum(a4), s5 = row16_sum(a5);
        float s6 = row16_sum(a6), s7 = row16_sum(a7);
        float h = fast_tanh(sel8(ks, s0, s1, s2, s3, s4, s5, s6, s7) + bj);
        u16 hbits = f2hb(h);
        if (writer) hcH[nx * 320 + woffH] = hbits;
        hreg[s] = hbits;
        if (s == 7) {
          if (writer) {
            u16* dst = hb + (size_t)(t - 7) * Hn + jcol;
            #pragma unroll
            for (int i = 0; i < 8; ++i) dst[i * Hn] = hreg[i];
          }
          if ((t8 & 3) == 3 && t8 < 127)
            ((uint2*)(xsH + (xcur ^ 1) * 2048))[tid] =
                make_uint2(h2bits(pk2(xr.x, xr.y)), h2bits(pk2(xr.z, xr.w)));
        }
        __syncthreads();  // vmcnt(0) drained -> safe to release
        if (s == 7 && (t8 & 3) == 3 && tid == 0)
          __hip_atomic_store(flags + b, (t8 >> 2) + 1, __ATOMIC_RELEASE,
                             __HIP_MEMORY_SCOPE_AGENT);
      }
    }
  } else {
    // ================= ROLE B: u2 = h1@Wx2 + b2 (f16 in place) ============
    const int b = blockIdx.x - Bn;
    u16* ub = h1b16 + (size_t)b * Tn * Hn;
    u16* hsH = smemU;  // [32][320] halfs = 20 KB

    h2 w2[8][8];
    #pragma unroll
    for (int p = 0; p < 8; ++p) {
      const float* r0 = Wx2 + (size_t)(16 * ks + 2 * p) * Hn + col0;
      float4 a0 = *(const float4*)r0, a1 = *(const float4*)(r0 + 4);
      float4 c0 = *(const float4*)(r0 + Hn), c1 = *(const float4*)(r0 + Hn + 4);
      w2[p][0] = pk2(a0.x, c0.x); w2[p][1] = pk2(a0.y, c0.y);
      w2[p][2] = pk2(a0.z, c0.z); w2[p][3] = pk2(a0.w, c0.w);
      w2[p][4] = pk2(a1.x, c1.x); w2[p][5] = pk2(a1.y, c1.y);
      w2[p][6] = pk2(a1.z, c1.z); w2[p][7] = pk2(a1.w, c1.w);
    }
    #pragma unroll
    for (int p = 0; p < 8; ++p)
      #pragma unroll
      for (int c = 0; c < 8; ++c) pin16(w2[p][c]);

    const float b2j = b2[jcol];
    const int lr = tid >> 4;            // step row within block
    const int lc = tid & 15;            // 16-half column chunk
    u16* ldst = hsH + lr * 320 + 20 * lc;

    u16 ureg[8];
    for (int blk = 0; blk < 32; ++blk) {
      if (tid == 0) {
        while (__hip_atomic_load(flags + b, __ATOMIC_ACQUIRE,
                                 __HIP_MEMORY_SCOPE_AGENT) < blk + 1)
          __builtin_amdgcn_s_sleep(8);
      }
      __syncthreads();
      {
        const uint4* src = (const uint4*)(ub + (size_t)(blk * 32 + lr) * Hn + 16 * lc);
        uint4 v0 = src[0], v1 = src[1];  // 32 B = 16 halfs
        ((uint2*)ldst)[0] = make_uint2(v0.x, v0.y);
        ((uint2*)ldst)[1] = make_uint2(v0.z, v0.w);
        ((uint2*)ldst)[2] = make_uint2(v1.x, v1.y);
        ((uint2*)ldst)[3] = make_uint2(v1.z, v1.w);
      }
      __syncthreads();
      for (int s = 0; s < 32; ++s) {
        const uint2* hq = (const uint2*)(hsH + s * 320 + 20 * ks);
        uint2 q0 = hq[0], q1 = hq[1], q2 = hq[2], q3 = hq[3];
        float a0 = 0.f, a1 = 0.f, a2 = 0.f, a3 = 0.f,
              a4 = 0.f, a5 = 0.f, a6 = 0.f, a7 = 0.f;
        const unsigned d[8] = {q0.x, q0.y, q1.x, q1.y, q2.x, q2.y, q3.x, q3.y};
        #pragma unroll
        for (int p = 0; p < 8; ++p) {
          h2 hp = bits2h(d[p]);
          a0 = fdot2(hp, w2[p][0], a0);
          a1 = fdot2(hp, w2[p][1], a1);
          a2 = fdot2(hp, w2[p][2], a2);
          a3 = fdot2(hp, w2[p][3], a3);
          a4 = fdot2(hp, w2[p][4], a4);
          a5 = fdot2(hp, w2[p][5], a5);
          a6 = fdot2(hp, w2[p][6], a6);
          a7 = fdot2(hp, w2[p][7], a7);
        }
        float s0 = row16_sum(a0), s1 = row16_sum(a1);
        float s2 = row16_sum(a2), s3 = row16_sum(a3);
        float s4 = row16_sum(a4), s5 = row16_sum(a5);
        float s6 = row16_sum(a6), s7 = row16_sum(a7);
        ureg[s & 7] = f2hb(sel8(ks, s0, s1, s2, s3, s4, s5, s6, s7) + b2j);
        if ((s & 7) == 7 && writer) {
          u16* dst = ub + (size_t)(blk * 32 + s - 7) * Hn + jcol;
          #pragma unroll
          for (int i = 0; i < 8; ++i) dst[i * Hn] = ureg[i];
        }
      }
      __syncthreads();  // drains u2 stores before next block's staging
    }
  }
}

// ---------------------------------------------------------------------------
// Scan 2: h2_t = tanh(u2_t + h2_{t-1}@Wh2), f16 weights/state, f32 math.
// ---------------------------------------------------------------------------
__global__ __launch_bounds__(512, 2) void scan2_kernel(
    const u16* __restrict__ U,      // [B,T,256] f16 = h1@Wx2 + b2
    const float* __restrict__ Wh2,  // [256,256] f32
    float* __restrict__ hfinal) {   // [B,256] f32
  __shared__ alignas(16) u16 hcU[640];  // 2 x 320 halfs
  const int tid = threadIdx.x;
  const int ks = tid & 15;
  const int cg = tid >> 4;
  const int col0 = 8 * cg;
  const int b = blockIdx.x;
  const u16* Ub = U + (size_t)b * Tn * Hn;

  h2 wh[8][8];
  #pragma unroll
  for (int p = 0; p < 8; ++p) {
    const float* r0 = Wh2 + (size_t)(16 * ks + 2 * p) * Hn + col0;
    float4 a0 = *(const float4*)r0, a1 = *(const float4*)(r0 + 4);
    float4 c0 = *(const float4*)(r0 + Hn), c1 = *(const float4*)(r0 + Hn + 4);
    wh[p][0] = pk2(a0.x, c0.x); wh[p][1] = pk2(a0.y, c0.y);
    wh[p][2] = pk2(a0.z, c0.z); wh[p][3] = pk2(a0.w, c0.w);
    wh[p][4] = pk2(a1.x, c1.x); wh[p][5] = pk2(a1.y, c1.y);
    wh[p][6] = pk2(a1.z, c1.z); wh[p][7] = pk2(a1.w, c1.w);
  }
  #pragma unroll
  for (int p = 0; p < 8; ++p)
    #pragma unroll
    for (int c = 0; c < 8; ++c) pin16(wh[p][c]);

  const int jcol = col0 + (ks & 7);
  const bool writer = (ks < 8);
  const int woffH = 20 * (jcol >> 4) + (jcol & 15);

  for (int i = tid; i < 640; i += 512) hcU[i] = 0;
  __syncthreads();

  float ucur[8], unxt[8];
  if (writer) {
    #pragma unroll
    for (int i = 0; i < 8; ++i) ucur[i] = hb2f(Ub[(size_t)i * Hn + jcol]);
  }

  for (int t8 = 0; t8 < 128; ++t8) {
    #pragma unroll
    for (int s = 0; s < 8; ++s) {
      const int cu = s & 1, nx = cu ^ 1;
      if (s == 0 && writer && t8 < 127) {
        #pragma unroll
        for (int i = 0; i < 8; ++i)
          unxt[i] = hb2f(Ub[(size_t)(t8 * 8 + 8 + i) * Hn + jcol]);
      }
      const uint2* hq = (const uint2*)(hcU + cu * 320 + 20 * ks);
      uint2 q0 = hq[0], q1 = hq[1], q2 = hq[2], q3 = hq[3];
      float a0 = 0.f, a1 = 0.f, a2 = 0.f, a3 = 0.f,
            a4 = 0.f, a5 = 0.f, a6 = 0.f, a7 = 0.f;
      const unsigned d[8] = {q0.x, q0.y, q1.x, q1.y, q2.x, q2.y, q3.x, q3.y};
      #pragma unroll
      for (int p = 0; p < 8; ++p) {
        h2 hp = bits2h(d[p]);
        a0 = fdot2(hp, wh[p][0], a0);
        a1 = fdot2(hp, wh[p][1], a1);
        a2 = fdot2(hp, wh[p][2], a2);
        a3 = fdot2(hp, wh[p][3], a3);
        a4 = fdot2(hp, wh[p][4], a4);
        a5 = fdot2(hp, wh[p][5], a5);
        a6 = fdot2(hp, wh[p][6], a6);
        a7 = fdot2(hp, wh[p][7], a7);
      }
      float s0 = row16_sum(a0), s1 = row16_sum(a1);
      float s2 = row16_sum(a2), s3 = row16_sum(a3);
      float s4 = row16_sum(a4), s5 = row16_sum(a5);
      float s6 = row16_sum(a6), s7 = row16_sum(a7);
      float h = fast_tanh(sel8(ks, s0, s1, s2, s3, s4, s5, s6, s7) + ucur[s]);
      if (writer) hcU[nx * 320 + woffH] = f2hb(h);
      if (s == 7) {
        #pragma unroll
        for (int i = 0; i < 8; ++i) ucur[i] = unxt[i];
      }
      __syncthreads();
    }
  }
  if (tid < Hn)
    hfinal[(size_t)b * Hn + tid] = hb2f(hcU[(tid >> 4) * 20 + (tid & 15)]);
}

// ---------------------------------------------------------------------------
// Head: out = softmax(h2_T @ Wd + bd). f32, unchanged.
// ---------------------------------------------------------------------------
__global__ __launch_bounds__(128) void head_kernel(
    const float* __restrict__ hfinal, const float* __restrict__ Wd,
    const float* __restrict__ bd, float* __restrict__ out) {
  __shared__ float hrow[Hn];
  __shared__ float red[On];
  const int o = threadIdx.x;
  const int b = blockIdx.x;
  hrow[o] = hfinal[(size_t)b * Hn + o];
  hrow[o + 128] = hfinal[(size_t)b * Hn + 128 + o];
  __syncthreads();
  float acc = bd[o];
  #pragma unroll 8
  for (int k = 0; k < Hn; ++k) acc = fmaf(hrow[k], Wd[(size_t)k * On + o], acc);
  red[o] = acc;
  __syncthreads();
  #pragma unroll
  for (int s = 64; s > 0; s >>= 1) {
    if (o < s) red[o] = fmaxf(red[o], red[o + s]);
    __syncthreads();
  }
  const float mx = red[0];
  __syncthreads();
  const float e = __expf(acc - mx);
  red[o] = e;
  __syncthreads();
  #pragma unroll
  for (int s = 64; s > 0; s >>= 1) {
    if (o < s) red[o] += red[o + s];
    __syncthreads();
  }
  out[(size_t)b * On + o] = e / red[0];
}

// ---------------------------------------------------------------------------
extern "C" void kernel_launch(void* const* d_in, const int* in_sizes, int n_in,
                              void* d_out, int out_size, void* d_ws, size_t ws_size,
                              hipStream_t stream) {
  const float* x   = (const float*)d_in[0];
  const float* Wx1 = (const float*)d_in[1];
  const float* Wh1 = (const float*)d_in[2];
  const float* b1  = (const float*)d_in[3];
  const float* Wx2 = (const float*)d_in[4];
  const float* Wh2 = (const float*)d_in[5];
  const float* b2  = (const float*)d_in[6];
  const float* Wd  = (const float*)d_in[7];
  const float* bd  = (const float*)d_in[8];
  float* out = (float*)d_out;

  u16* h1b16 = (u16*)d_ws;                            // [B,T,256] f16 (64 MB)
  float* hfinal = (float*)(h1b16 + (size_t)Bn * Tn * Hn);  // [B,256] f32
  int* flags = (int*)(hfinal + (size_t)Bn * Hn);      // [B]

  hipMemsetAsync(flags, 0, Bn * sizeof(int), stream);
  stage1_kernel<<<2 * Bn, 512, 0, stream>>>(x, Wx1, Wh1, b1, Wx2, b2, h1b16, flags);
  scan2_kernel<<<Bn, 512, 0, stream>>>(h1b16, Wh2, hfinal);
  head_kernel<<<Bn, 128, 0, stream>>>(hfinal, Wd, bd, out);
}